// Round 1
// baseline (303.806 us; speedup 1.0000x reference)
//
#include <hip/hip_runtime.h>
#include <hip/hip_fp16.h>

typedef _Float16 f16;
typedef _Float16 f16x8 __attribute__((ext_vector_type(8)));
typedef _Float16 f16x4 __attribute__((ext_vector_type(4)));
typedef float f32x4 __attribute__((ext_vector_type(4)));

#define LN_EPS 1e-5f

__device__ __forceinline__ float gelu_exact(float v) {
    return 0.5f * v * (1.0f + erff(v * 0.70710678118654752440f));
}

// ---------------- LayerNorm(x) -> y_h (fp16), plus x -> x_h (fp16) ----------
// one block (256 threads) per row of 1024 floats; each thread owns 4 elems
__global__ __launch_bounds__(256)
void ln_cast_kernel(const float* __restrict__ x,
                    const float* __restrict__ gamma,
                    const float* __restrict__ beta,
                    f16* __restrict__ y_h,
                    f16* __restrict__ x_h) {
    const int row = blockIdx.x;
    const int t = threadIdx.x;
    const size_t base = (size_t)row * 1024;
    float4 v = ((const float4*)(x + base))[t];
    float s  = v.x + v.y + v.z + v.w;
    float s2 = v.x*v.x + v.y*v.y + v.z*v.z + v.w*v.w;
    #pragma unroll
    for (int off = 32; off > 0; off >>= 1) {
        s  += __shfl_down(s, off, 64);
        s2 += __shfl_down(s2, off, 64);
    }
    __shared__ float ls[4], ls2[4];
    const int wid = t >> 6;
    if ((t & 63) == 0) { ls[wid] = s; ls2[wid] = s2; }
    __syncthreads();
    if (t == 0) {
        ls[0]  = ls[0] + ls[1] + ls[2] + ls[3];
        ls2[0] = ls2[0] + ls2[1] + ls2[2] + ls2[3];
    }
    __syncthreads();
    const float mu   = ls[0] * (1.0f / 1024.0f);
    const float var  = ls2[0] * (1.0f / 1024.0f) - mu * mu;
    const float rstd = rsqrtf(var + LN_EPS);
    const float4 g  = ((const float4*)gamma)[t];
    const float4 bt = ((const float4*)beta)[t];
    f16x4 yo, xo;
    yo[0] = (f16)((v.x - mu) * rstd * g.x + bt.x);
    yo[1] = (f16)((v.y - mu) * rstd * g.y + bt.y);
    yo[2] = (f16)((v.z - mu) * rstd * g.z + bt.z);
    yo[3] = (f16)((v.w - mu) * rstd * g.w + bt.w);
    xo[0] = (f16)v.x; xo[1] = (f16)v.y; xo[2] = (f16)v.z; xo[3] = (f16)v.w;
    *(f16x4*)(y_h + base + t * 4) = yo;
    *(f16x4*)(x_h + base + t * 4) = xo;
}

// ---------------- final LayerNorm: pre (fp32) -> out (fp32) ----------------
__global__ __launch_bounds__(256)
void ln_final_kernel(const float* __restrict__ pre,
                     const float* __restrict__ gamma,
                     const float* __restrict__ beta,
                     float* __restrict__ out) {
    const int row = blockIdx.x;
    const int t = threadIdx.x;
    const size_t base = (size_t)row * 1024;
    float4 v = ((const float4*)(pre + base))[t];
    float s  = v.x + v.y + v.z + v.w;
    float s2 = v.x*v.x + v.y*v.y + v.z*v.z + v.w*v.w;
    #pragma unroll
    for (int off = 32; off > 0; off >>= 1) {
        s  += __shfl_down(s, off, 64);
        s2 += __shfl_down(s2, off, 64);
    }
    __shared__ float ls[4], ls2[4];
    const int wid = t >> 6;
    if ((t & 63) == 0) { ls[wid] = s; ls2[wid] = s2; }
    __syncthreads();
    if (t == 0) {
        ls[0]  = ls[0] + ls[1] + ls[2] + ls[3];
        ls2[0] = ls2[0] + ls2[1] + ls2[2] + ls2[3];
    }
    __syncthreads();
    const float mu   = ls[0] * (1.0f / 1024.0f);
    const float var  = ls2[0] * (1.0f / 1024.0f) - mu * mu;
    const float rstd = rsqrtf(var + LN_EPS);
    const float4 g  = ((const float4*)gamma)[t];
    const float4 bt = ((const float4*)beta)[t];
    float4 o;
    o.x = (v.x - mu) * rstd * g.x + bt.x;
    o.y = (v.y - mu) * rstd * g.y + bt.y;
    o.z = (v.z - mu) * rstd * g.z + bt.z;
    o.w = (v.w - mu) * rstd * g.w + bt.w;
    ((float4*)(out + base))[t] = o;
}

// ------------- transpose + cast fp32 [R,C] -> fp16 [C,R] -------------------
__global__ __launch_bounds__(256)
void transpose_cast_kernel(const float* __restrict__ src,
                           f16* __restrict__ dst, int R, int C) {
    __shared__ float tile[32][33];
    const int c0 = blockIdx.x * 32, r0 = blockIdx.y * 32;
    const int tx = threadIdx.x & 31, ty = threadIdx.x >> 5;  // ty in [0,8)
    #pragma unroll
    for (int i = 0; i < 4; ++i) {
        const int r = ty + i * 8;
        tile[r][tx] = src[(size_t)(r0 + r) * C + c0 + tx];
    }
    __syncthreads();
    #pragma unroll
    for (int i = 0; i < 4; ++i) {
        const int r = ty + i * 8;
        dst[(size_t)(c0 + r) * R + r0 + tx] = (f16)tile[tx][r];
    }
}

// ------------- batched transpose fp16 [R,C] -> fp16 [C,R] ------------------
__global__ __launch_bounds__(256)
void transpose_f16_kernel(const f16* __restrict__ src,
                          f16* __restrict__ dst, int R, int C) {
    __shared__ f16 tile[32][33];
    const size_t zb = (size_t)blockIdx.z * R * C;
    src += zb; dst += zb;
    const int c0 = blockIdx.x * 32, r0 = blockIdx.y * 32;
    const int tx = threadIdx.x & 31, ty = threadIdx.x >> 5;
    #pragma unroll
    for (int i = 0; i < 4; ++i) {
        const int r = ty + i * 8;
        tile[r][tx] = src[(size_t)(r0 + r) * C + c0 + tx];
    }
    __syncthreads();
    #pragma unroll
    for (int i = 0; i < 4; ++i) {
        const int r = ty + i * 8;
        dst[(size_t)(c0 + r) * R + r0 + tx] = tile[tx][r];
    }
}

// ---------------- GEMM (NT): out[m][n] = sum_k A[m][k] * Bt[n][k] ----------
// 128x128 tile, BK=32, 256 threads = 4 waves (2x2), wave tile 64x64,
// v_mfma_f32_16x16x32_f16, fp32 accum.
// EPI: 0 = +bias, exact GELU, fp16 out
//      1 = +bias, fp16 out
//      2 = fp16 out
//      3 = + xadd (fp32), fp32 out
template <int EPI>
__global__ __launch_bounds__(256)
void gemm_nt_kernel(const f16* __restrict__ A, const f16* __restrict__ Bt,
                    const float* __restrict__ bias,
                    const float* __restrict__ xadd,
                    f16* __restrict__ outH, float* __restrict__ outF,
                    int M, int N, int K,
                    long long batchA, long long batchB, long long batchC) {
    __shared__ __attribute__((aligned(16))) f16 sA[128][40];
    __shared__ __attribute__((aligned(16))) f16 sB[128][40];

    const int z = blockIdx.z;
    A  += (size_t)z * batchA;
    Bt += (size_t)z * batchB;

    const int m0 = blockIdx.x * 128;
    const int n0 = blockIdx.y * 128;
    const int t = threadIdx.x;
    const int l = t & 63;
    const int wid = t >> 6;
    const int wm = (wid >> 1) * 64;
    const int wn = (wid & 1) * 64;

    f32x4 acc[4][4] = {};

    const int rl = l & 15;
    const int ko = (l >> 4) * 8;
    const int nk = K >> 5;

    for (int kt = 0; kt < nk; ++kt) {
        // stage A-tile and Bt-tile: 512 chunks of 16B each, 2 per thread
        #pragma unroll
        for (int i = 0; i < 2; ++i) {
            const int c = t + i * 256;
            const int row = c >> 2;
            const int k8 = (c & 3) << 3;
            const uint4 va = *(const uint4*)(A  + (size_t)(m0 + row) * K + kt * 32 + k8);
            *(uint4*)&sA[row][k8] = va;
            const uint4 vb = *(const uint4*)(Bt + (size_t)(n0 + row) * K + kt * 32 + k8);
            *(uint4*)&sB[row][k8] = vb;
        }
        __syncthreads();
        f16x8 a[4], b[4];
        #pragma unroll
        for (int f = 0; f < 4; ++f) {
            a[f] = *(const f16x8*)&sA[wm + f * 16 + rl][ko];
            b[f] = *(const f16x8*)&sB[wn + f * 16 + rl][ko];
        }
        #pragma unroll
        for (int fm = 0; fm < 4; ++fm)
            #pragma unroll
            for (int fn = 0; fn < 4; ++fn)
                acc[fm][fn] = __builtin_amdgcn_mfma_f32_16x16x32_f16(
                    a[fm], b[fn], acc[fm][fn], 0, 0, 0);
        __syncthreads();
    }

    // epilogue: D mapping col = l&15, row = (l>>4)*4 + r
    const int rh = l >> 4;
    const float* xaddz = xadd;
    f16* outHz = outH;
    float* outFz = outF;
    if (EPI == 3) {
        outFz += (size_t)z * batchC;
        xaddz += (size_t)z * batchC;
    } else {
        outHz += (size_t)z * batchC;
    }
    #pragma unroll
    for (int fm = 0; fm < 4; ++fm) {
        #pragma unroll
        for (int fn = 0; fn < 4; ++fn) {
            const int col = n0 + wn + fn * 16 + rl;
            #pragma unroll
            for (int r = 0; r < 4; ++r) {
                const int row = m0 + wm + fm * 16 + rh * 4 + r;
                float v = acc[fm][fn][r];
                const size_t idx = (size_t)row * N + col;
                if (EPI == 0) {
                    v += bias[col];
                    outHz[idx] = (f16)gelu_exact(v);
                } else if (EPI == 1) {
                    v += bias[col];
                    outHz[idx] = (f16)v;
                } else if (EPI == 2) {
                    outHz[idx] = (f16)v;
                } else {
                    outFz[idx] = v + xaddz[idx];
                }
            }
        }
    }
}

extern "C" void kernel_launch(void* const* d_in, const int* in_sizes, int n_in,
                              void* d_out, int out_size, void* d_ws, size_t ws_size,
                              hipStream_t stream) {
    const float* x     = (const float*)d_in[0];
    const float* gamma = (const float*)d_in[1];
    const float* beta  = (const float*)d_in[2];
    const float* w1    = (const float*)d_in[3];
    const float* b1    = (const float*)d_in[4];
    const float* w2    = (const float*)d_in[5];
    const float* b2    = (const float*)d_in[6];
    float* out = (float*)d_out;

    const int BS = 4, T = 2048, DIM = 1024, HID = 2048;
    const int M = BS * T;  // 8192

    // workspace layout (bytes); total 120 MiB
    char* ws = (char*)d_ws;
    f16*   x_h    = (f16*)(ws + 0);                       // 16 MiB [M,DIM]
    f16*   y_h    = (f16*)(ws + (size_t)16 * 1024 * 1024); // 16 MiB [M,DIM]
    f16*   y2t    = y_h;                                   // alias: [BS,DIM,T], y_h dead after GEMM1
    f16*   h      = (f16*)(ws + (size_t)32 * 1024 * 1024); // 32 MiB [M,HID]
    float* pre    = (float*)h;                             // alias: 32 MiB [M,DIM] fp32, h dead after GEMM2
    f16*   y2     = (f16*)(ws + (size_t)64 * 1024 * 1024); // 16 MiB [M,DIM]
    f16*   scores = (f16*)(ws + (size_t)80 * 1024 * 1024); // 32 MiB [BS,T,T]
    f16*   w1t    = (f16*)(ws + (size_t)112 * 1024 * 1024);// 4 MiB [HID,DIM]
    f16*   w2t    = (f16*)(ws + (size_t)116 * 1024 * 1024);// 4 MiB [DIM,HID]

    // 1) first LN + casts
    ln_cast_kernel<<<M, 256, 0, stream>>>(x, gamma, beta, y_h, x_h);

    // 2) weight transposes to fp16 [N,K]
    transpose_cast_kernel<<<dim3(HID / 32, DIM / 32), 256, 0, stream>>>(w1, w1t, DIM, HID);
    transpose_cast_kernel<<<dim3(DIM / 32, HID / 32), 256, 0, stream>>>(w2, w2t, HID, DIM);

    // 3) h = gelu(y @ w1 + b1)   [M,HID]
    gemm_nt_kernel<0><<<dim3(M / 128, HID / 128, 1), 256, 0, stream>>>(
        y_h, w1t, b1, nullptr, h, nullptr, M, HID, DIM, 0, 0, 0);

    // 4) y2 = h @ w2 + b2        [M,DIM]
    gemm_nt_kernel<1><<<dim3(M / 128, DIM / 128, 1), 256, 0, stream>>>(
        h, w2t, b2, nullptr, y2, nullptr, M, DIM, HID, 0, 0, 0);

    // 5) y2t per batch: [T,DIM] -> [DIM,T]
    transpose_f16_kernel<<<dim3(DIM / 32, T / 32, BS), 256, 0, stream>>>(y2, y2t, T, DIM);

    // 6) scores = x @ x^T per batch   [T,T]
    gemm_nt_kernel<2><<<dim3(T / 128, T / 128, BS), 256, 0, stream>>>(
        x_h, x_h, nullptr, nullptr, scores, nullptr, T, T, DIM,
        (long long)T * DIM, (long long)T * DIM, (long long)T * T);

    // 7) pre = scores @ y2 + x per batch   [T,DIM] fp32
    gemm_nt_kernel<3><<<dim3(T / 128, DIM / 128, BS), 256, 0, stream>>>(
        scores, y2t, nullptr, x, nullptr, pre, T, DIM, T,
        (long long)T * T, (long long)DIM * T, (long long)T * DIM);

    // 8) final LN
    ln_final_kernel<<<M, 256, 0, stream>>>(pre, gamma, beta, out);
}

// Round 2
// 253.098 us; speedup vs baseline: 1.2003x; 1.2003x over previous
//
#include <hip/hip_runtime.h>
#include <hip/hip_fp16.h>

typedef _Float16 f16;
typedef _Float16 f16x8 __attribute__((ext_vector_type(8)));
typedef _Float16 f16x4 __attribute__((ext_vector_type(4)));
typedef float f32x4 __attribute__((ext_vector_type(4)));

#define LN_EPS 1e-5f

__device__ __forceinline__ float gelu_exact(float v) {
    return 0.5f * v * (1.0f + erff(v * 0.70710678118654752440f));
}

// async global -> LDS, 16B per lane; lds dest must be wave-uniform base (+lane*16 by HW)
__device__ __forceinline__ void gload_lds16(const f16* g, f16* l) {
    __builtin_amdgcn_global_load_lds(
        (const __attribute__((address_space(1))) unsigned int*)(g),
        (__attribute__((address_space(3))) unsigned int*)(l),
        16, 0, 0);
}

// ---------------- LayerNorm(x) -> y_h (fp16), plus x -> x_h (fp16) ----------
__global__ __launch_bounds__(256)
void ln_cast_kernel(const float* __restrict__ x,
                    const float* __restrict__ gamma,
                    const float* __restrict__ beta,
                    f16* __restrict__ y_h,
                    f16* __restrict__ x_h) {
    const int row = blockIdx.x;
    const int t = threadIdx.x;
    const size_t base = (size_t)row * 1024;
    float4 v = ((const float4*)(x + base))[t];
    float s  = v.x + v.y + v.z + v.w;
    float s2 = v.x*v.x + v.y*v.y + v.z*v.z + v.w*v.w;
    #pragma unroll
    for (int off = 32; off > 0; off >>= 1) {
        s  += __shfl_down(s, off, 64);
        s2 += __shfl_down(s2, off, 64);
    }
    __shared__ float ls[4], ls2[4];
    const int wid = t >> 6;
    if ((t & 63) == 0) { ls[wid] = s; ls2[wid] = s2; }
    __syncthreads();
    if (t == 0) {
        ls[0]  = ls[0] + ls[1] + ls[2] + ls[3];
        ls2[0] = ls2[0] + ls2[1] + ls2[2] + ls2[3];
    }
    __syncthreads();
    const float mu   = ls[0] * (1.0f / 1024.0f);
    const float var  = ls2[0] * (1.0f / 1024.0f) - mu * mu;
    const float rstd = rsqrtf(var + LN_EPS);
    const float4 g  = ((const float4*)gamma)[t];
    const float4 bt = ((const float4*)beta)[t];
    f16x4 yo, xo;
    yo[0] = (f16)((v.x - mu) * rstd * g.x + bt.x);
    yo[1] = (f16)((v.y - mu) * rstd * g.y + bt.y);
    yo[2] = (f16)((v.z - mu) * rstd * g.z + bt.z);
    yo[3] = (f16)((v.w - mu) * rstd * g.w + bt.w);
    xo[0] = (f16)v.x; xo[1] = (f16)v.y; xo[2] = (f16)v.z; xo[3] = (f16)v.w;
    *(f16x4*)(y_h + base + t * 4) = yo;
    *(f16x4*)(x_h + base + t * 4) = xo;
}

// ---------------- final LayerNorm: pre (fp32) -> out (fp32) ----------------
__global__ __launch_bounds__(256)
void ln_final_kernel(const float* __restrict__ pre,
                     const float* __restrict__ gamma,
                     const float* __restrict__ beta,
                     float* __restrict__ out) {
    const int row = blockIdx.x;
    const int t = threadIdx.x;
    const size_t base = (size_t)row * 1024;
    float4 v = ((const float4*)(pre + base))[t];
    float s  = v.x + v.y + v.z + v.w;
    float s2 = v.x*v.x + v.y*v.y + v.z*v.z + v.w*v.w;
    #pragma unroll
    for (int off = 32; off > 0; off >>= 1) {
        s  += __shfl_down(s, off, 64);
        s2 += __shfl_down(s2, off, 64);
    }
    __shared__ float ls[4], ls2[4];
    const int wid = t >> 6;
    if ((t & 63) == 0) { ls[wid] = s; ls2[wid] = s2; }
    __syncthreads();
    if (t == 0) {
        ls[0]  = ls[0] + ls[1] + ls[2] + ls[3];
        ls2[0] = ls2[0] + ls2[1] + ls2[2] + ls2[3];
    }
    __syncthreads();
    const float mu   = ls[0] * (1.0f / 1024.0f);
    const float var  = ls2[0] * (1.0f / 1024.0f) - mu * mu;
    const float rstd = rsqrtf(var + LN_EPS);
    const float4 g  = ((const float4*)gamma)[t];
    const float4 bt = ((const float4*)beta)[t];
    float4 o;
    o.x = (v.x - mu) * rstd * g.x + bt.x;
    o.y = (v.y - mu) * rstd * g.y + bt.y;
    o.z = (v.z - mu) * rstd * g.z + bt.z;
    o.w = (v.w - mu) * rstd * g.w + bt.w;
    ((float4*)(out + base))[t] = o;
}

// ------------- transpose + cast fp32 [R,C] -> fp16 [C,R] -------------------
__global__ __launch_bounds__(256)
void transpose_cast_kernel(const float* __restrict__ src,
                           f16* __restrict__ dst, int R, int C) {
    __shared__ float tile[32][33];
    const int c0 = blockIdx.x * 32, r0 = blockIdx.y * 32;
    const int tx = threadIdx.x & 31, ty = threadIdx.x >> 5;
    #pragma unroll
    for (int i = 0; i < 4; ++i) {
        const int r = ty + i * 8;
        tile[r][tx] = src[(size_t)(r0 + r) * C + c0 + tx];
    }
    __syncthreads();
    #pragma unroll
    for (int i = 0; i < 4; ++i) {
        const int r = ty + i * 8;
        dst[(size_t)(c0 + r) * R + r0 + tx] = (f16)tile[tx][r];
    }
}

// ------------- batched transpose fp16 [R,C] -> fp16 [C,R] ------------------
__global__ __launch_bounds__(256)
void transpose_f16_kernel(const f16* __restrict__ src,
                          f16* __restrict__ dst, int R, int C) {
    __shared__ f16 tile[32][33];
    const size_t zb = (size_t)blockIdx.z * R * C;
    src += zb; dst += zb;
    const int c0 = blockIdx.x * 32, r0 = blockIdx.y * 32;
    const int tx = threadIdx.x & 31, ty = threadIdx.x >> 5;
    #pragma unroll
    for (int i = 0; i < 4; ++i) {
        const int r = ty + i * 8;
        tile[r][tx] = src[(size_t)(r0 + r) * C + c0 + tx];
    }
    __syncthreads();
    #pragma unroll
    for (int i = 0; i < 4; ++i) {
        const int r = ty + i * 8;
        dst[(size_t)(c0 + r) * R + r0 + tx] = tile[tx][r];
    }
}

// ---------------- GEMM (NT): out[m][n] = sum_k A[m][k] * Bt[n][k] ----------
// m97 structure: 128x128 tile, BK=32, 256 threads = 4 waves (2x2),
// global_load_lds width-16 into LINEAR LDS [128][32], mfma_f32_16x16x32_f16.
// EPI: 0 = +bias, exact GELU, fp16 out [M][N]
//      1 = +bias, fp16 out TRANSPOSED per batch: out[z][col][row%2048] (T=2048)
//      2 = fp16 out [M][N] (batched)
//      3 = fp32 out + xadd (batched)
template <int EPI>
__global__ __launch_bounds__(256)
void gemm_nt_kernel(const f16* __restrict__ A, const f16* __restrict__ Bt,
                    const float* __restrict__ bias,
                    const float* __restrict__ xadd,
                    f16* __restrict__ outH, float* __restrict__ outF,
                    int M, int N, int K,
                    long long batchA, long long batchB, long long batchC) {
    __shared__ __attribute__((aligned(16))) f16 sA[128 * 32];
    __shared__ __attribute__((aligned(16))) f16 sB[128 * 32];

    const int z = blockIdx.z;
    A  += (size_t)z * batchA;
    Bt += (size_t)z * batchB;

    const int m0 = blockIdx.x * 128;
    const int n0 = blockIdx.y * 128;
    const int t = threadIdx.x;
    const int l = t & 63;
    const int wid = t >> 6;
    const int wm = (wid >> 1) * 64;
    const int wn = (wid & 1) * 64;

    f32x4 acc[4][4] = {};

    const int rl = l & 15;
    const int ko = (l >> 4) * 8;
    const int nk = K >> 5;

    // staging addresses: chunk c = i*256 + t covers 16B at LDS byte c*16,
    // i.e. row = c>>2, k8 = (c&3)*8 of the [128][32] f16 tile.
    const int c0 = t, c1 = t + 256;
    const f16* Ag0 = A  + (size_t)(m0 + (c0 >> 2)) * K + (c0 & 3) * 8;
    const f16* Ag1 = A  + (size_t)(m0 + (c1 >> 2)) * K + (c1 & 3) * 8;
    const f16* Bg0 = Bt + (size_t)(n0 + (c0 >> 2)) * K + (c0 & 3) * 8;
    const f16* Bg1 = Bt + (size_t)(n0 + (c1 >> 2)) * K + (c1 & 3) * 8;
    // wave-uniform LDS bases (HW adds lane*16B)
    f16* lA0 = sA + (size_t)(wid * 64) * 8;
    f16* lA1 = sA + (size_t)(256 + wid * 64) * 8;
    f16* lB0 = sB + (size_t)(wid * 64) * 8;
    f16* lB1 = sB + (size_t)(256 + wid * 64) * 8;

    for (int kt = 0; kt < nk; ++kt) {
        const int kof = kt * 32;
        gload_lds16(Ag0 + kof, lA0);
        gload_lds16(Ag1 + kof, lA1);
        gload_lds16(Bg0 + kof, lB0);
        gload_lds16(Bg1 + kof, lB1);
        __syncthreads();   // drains vmcnt(0): tiles visible to all waves
        f16x8 a[4], b[4];
        #pragma unroll
        for (int f = 0; f < 4; ++f) {
            a[f] = *(const f16x8*)&sA[(wm + f * 16 + rl) * 32 + ko];
            b[f] = *(const f16x8*)&sB[(wn + f * 16 + rl) * 32 + ko];
        }
        #pragma unroll
        for (int fm = 0; fm < 4; ++fm)
            #pragma unroll
            for (int fn = 0; fn < 4; ++fn)
                acc[fm][fn] = __builtin_amdgcn_mfma_f32_16x16x32_f16(
                    a[fm], b[fn], acc[fm][fn], 0, 0, 0);
        __syncthreads();   // protect LDS before next-tile staging
    }

    // epilogue: D mapping col = l&15, row = (l>>4)*4 + r
    const int rh = l >> 4;
    const float* xaddz = xadd;
    f16* outHz = outH;
    float* outFz = outF;
    if (EPI == 3) {
        outFz += (size_t)z * batchC;
        xaddz += (size_t)z * batchC;
    } else if (EPI == 2) {
        outHz += (size_t)z * batchC;
    }
    #pragma unroll
    for (int fm = 0; fm < 4; ++fm) {
        #pragma unroll
        for (int fn = 0; fn < 4; ++fn) {
            const int col = n0 + wn + fn * 16 + rl;
            if (EPI == 1) {
                // transposed-per-batch write: rows (r=0..3) are consecutive
                // along T -> one f16x4 store. T = 2048 hardcoded.
                const int row0 = m0 + wm + fm * 16 + rh * 4;
                const int zz = row0 >> 11;
                const int rr = row0 & 2047;
                const float bv = bias[col];
                f16x4 o;
                #pragma unroll
                for (int r = 0; r < 4; ++r) o[r] = (f16)(acc[fm][fn][r] + bv);
                *(f16x4*)(outH + ((size_t)zz * N + col) * 2048 + rr) = o;
            } else {
                #pragma unroll
                for (int r = 0; r < 4; ++r) {
                    const int row = m0 + wm + fm * 16 + rh * 4 + r;
                    float v = acc[fm][fn][r];
                    const size_t idx = (size_t)row * N + col;
                    if (EPI == 0) {
                        v += bias[col];
                        outHz[idx] = (f16)gelu_exact(v);
                    } else if (EPI == 2) {
                        outHz[idx] = (f16)v;
                    } else {
                        outFz[idx] = v + xaddz[idx];
                    }
                }
            }
        }
    }
}

extern "C" void kernel_launch(void* const* d_in, const int* in_sizes, int n_in,
                              void* d_out, int out_size, void* d_ws, size_t ws_size,
                              hipStream_t stream) {
    const float* x     = (const float*)d_in[0];
    const float* gamma = (const float*)d_in[1];
    const float* beta  = (const float*)d_in[2];
    const float* w1    = (const float*)d_in[3];
    const float* b1    = (const float*)d_in[4];
    const float* w2    = (const float*)d_in[5];
    const float* b2    = (const float*)d_in[6];
    float* out = (float*)d_out;

    const int BS = 4, T = 2048, DIM = 1024, HID = 2048;
    const int M = BS * T;  // 8192
    const long long MB = 1024 * 1024;

    // workspace layout (112 MiB total)
    char* ws = (char*)d_ws;
    f16*   x_h  = (f16*)(ws + 0 * MB);    // 16 MiB [M][DIM]
    f16*   y_h  = (f16*)(ws + 16 * MB);   // 16 MiB [M][DIM]
    f16*   h    = (f16*)(ws + 32 * MB);   // 32 MiB [M][HID]
    float* pre  = (float*)h;              // alias: h dead after GEMM2
    f16*   y2t  = (f16*)(ws + 64 * MB);   // 16 MiB [BS][DIM][T]
    f16*   x_t  = (f16*)(ws + 80 * MB);   // 16 MiB [BS][DIM][T]
    f16*   G    = (f16*)(ws + 96 * MB);   // 8 MiB  [BS][DIM][DIM]  (G' = y2^T x per batch)
    f16*   w1t  = (f16*)(ws + 104 * MB);  // 4 MiB  [HID][DIM]
    f16*   w2t  = (f16*)(ws + 108 * MB);  // 4 MiB  [DIM][HID]

    // 1) first LN + fp16 casts
    ln_cast_kernel<<<M, 256, 0, stream>>>(x, gamma, beta, y_h, x_h);

    // 2) weight transposes to fp16 [N][K]
    transpose_cast_kernel<<<dim3(HID / 32, DIM / 32), 256, 0, stream>>>(w1, w1t, DIM, HID);
    transpose_cast_kernel<<<dim3(DIM / 32, HID / 32), 256, 0, stream>>>(w2, w2t, HID, DIM);

    // 3) h = gelu(y @ w1 + b1)   [M][HID]
    gemm_nt_kernel<0><<<dim3(M / 128, HID / 128, 1), 256, 0, stream>>>(
        y_h, w1t, b1, nullptr, h, nullptr, M, HID, DIM, 0, 0, 0);

    // 4) y2t[z][f][t] = (h @ w2 + b2)[z*T+t][f]   (transposed epilogue)
    gemm_nt_kernel<1><<<dim3(M / 128, DIM / 128, 1), 256, 0, stream>>>(
        h, w2t, b2, nullptr, y2t, nullptr, M, DIM, HID, 0, 0, 0);

    // 5) x_t[z][f][t] = x_h[z*T+t][f]
    transpose_f16_kernel<<<dim3(DIM / 32, T / 32, BS), 256, 0, stream>>>(x_h, x_t, T, DIM);

    // 6) G'[z][f2][f1] = sum_t y2t[z][f2][t] * x_t[z][f1][t]   ( = (x^T y2)^T )
    gemm_nt_kernel<2><<<dim3(DIM / 128, DIM / 128, BS), 256, 0, stream>>>(
        y2t, x_t, nullptr, nullptr, G, nullptr, DIM, DIM, T,
        (long long)DIM * T, (long long)DIM * T, (long long)DIM * DIM);

    // 7) pre[z][t][f] = sum_k x_h[z][t][k] * G'[z][f][k] + x   (= x (x^T y2) + x)
    gemm_nt_kernel<3><<<dim3(T / 128, DIM / 128, BS), 256, 0, stream>>>(
        x_h, G, nullptr, x, nullptr, pre, T, DIM, DIM,
        (long long)T * DIM, (long long)DIM * DIM, (long long)T * DIM);

    // 8) final LN
    ln_final_kernel<<<M, 256, 0, stream>>>(pre, gamma, beta, out);
}

// Round 3
// 244.474 us; speedup vs baseline: 1.2427x; 1.0353x over previous
//
#include <hip/hip_runtime.h>
#include <hip/hip_fp16.h>

typedef _Float16 f16;
typedef _Float16 f16x8 __attribute__((ext_vector_type(8)));
typedef _Float16 f16x4 __attribute__((ext_vector_type(4)));
typedef float f32x4 __attribute__((ext_vector_type(4)));

#define LN_EPS 1e-5f

// erf via Abramowitz-Stegun 7.1.26 (|eps| <= 1.5e-7), ~12 VALU incl v_exp/v_rcp
__device__ __forceinline__ float erf_fast(float x) {
    const float ax = __builtin_fabsf(x);
    const float t = 1.0f / (1.0f + 0.3275911f * ax);
    const float y = t * (0.254829592f +
                    t * (-0.284496736f +
                    t * (1.421413741f +
                    t * (-1.453152027f +
                    t * 1.061405429f))));
    const float r = 1.0f - y * __expf(-ax * ax);
    return __builtin_copysignf(r, x);
}

__device__ __forceinline__ float gelu_exact(float v) {
    return 0.5f * v * (1.0f + erf_fast(v * 0.70710678118654752440f));
}

// async global -> LDS, 16B per lane; lds dest is wave-uniform base (+lane*16 by HW)
__device__ __forceinline__ void gload_lds16(const f16* g, f16* l) {
    __builtin_amdgcn_global_load_lds(
        (const __attribute__((address_space(1))) unsigned int*)(g),
        (__attribute__((address_space(3))) unsigned int*)(l),
        16, 0, 0);
}

// ---------------- LayerNorm(x) -> y_h (fp16), plus x -> x_h (fp16) ----------
__global__ __launch_bounds__(256)
void ln_cast_kernel(const float* __restrict__ x,
                    const float* __restrict__ gamma,
                    const float* __restrict__ beta,
                    f16* __restrict__ y_h,
                    f16* __restrict__ x_h) {
    const int row = blockIdx.x;
    const int t = threadIdx.x;
    const size_t base = (size_t)row * 1024;
    float4 v = ((const float4*)(x + base))[t];
    float s  = v.x + v.y + v.z + v.w;
    float s2 = v.x*v.x + v.y*v.y + v.z*v.z + v.w*v.w;
    #pragma unroll
    for (int off = 32; off > 0; off >>= 1) {
        s  += __shfl_down(s, off, 64);
        s2 += __shfl_down(s2, off, 64);
    }
    __shared__ float ls[4], ls2[4];
    const int wid = t >> 6;
    if ((t & 63) == 0) { ls[wid] = s; ls2[wid] = s2; }
    __syncthreads();
    if (t == 0) {
        ls[0]  = ls[0] + ls[1] + ls[2] + ls[3];
        ls2[0] = ls2[0] + ls2[1] + ls2[2] + ls2[3];
    }
    __syncthreads();
    const float mu   = ls[0] * (1.0f / 1024.0f);
    const float var  = ls2[0] * (1.0f / 1024.0f) - mu * mu;
    const float rstd = rsqrtf(var + LN_EPS);
    const float4 g  = ((const float4*)gamma)[t];
    const float4 bt = ((const float4*)beta)[t];
    f16x4 yo, xo;
    yo[0] = (f16)((v.x - mu) * rstd * g.x + bt.x);
    yo[1] = (f16)((v.y - mu) * rstd * g.y + bt.y);
    yo[2] = (f16)((v.z - mu) * rstd * g.z + bt.z);
    yo[3] = (f16)((v.w - mu) * rstd * g.w + bt.w);
    xo[0] = (f16)v.x; xo[1] = (f16)v.y; xo[2] = (f16)v.z; xo[3] = (f16)v.w;
    *(f16x4*)(y_h + base + t * 4) = yo;
    *(f16x4*)(x_h + base + t * 4) = xo;
}

// ---------------- final LayerNorm: pre (fp32) -> out (fp32) ----------------
__global__ __launch_bounds__(256)
void ln_final_kernel(const float* __restrict__ pre,
                     const float* __restrict__ gamma,
                     const float* __restrict__ beta,
                     float* __restrict__ out) {
    const int row = blockIdx.x;
    const int t = threadIdx.x;
    const size_t base = (size_t)row * 1024;
    float4 v = ((const float4*)(pre + base))[t];
    float s  = v.x + v.y + v.z + v.w;
    float s2 = v.x*v.x + v.y*v.y + v.z*v.z + v.w*v.w;
    #pragma unroll
    for (int off = 32; off > 0; off >>= 1) {
        s  += __shfl_down(s, off, 64);
        s2 += __shfl_down(s2, off, 64);
    }
    __shared__ float ls[4], ls2[4];
    const int wid = t >> 6;
    if ((t & 63) == 0) { ls[wid] = s; ls2[wid] = s2; }
    __syncthreads();
    if (t == 0) {
        ls[0]  = ls[0] + ls[1] + ls[2] + ls[3];
        ls2[0] = ls2[0] + ls2[1] + ls2[2] + ls2[3];
    }
    __syncthreads();
    const float mu   = ls[0] * (1.0f / 1024.0f);
    const float var  = ls2[0] * (1.0f / 1024.0f) - mu * mu;
    const float rstd = rsqrtf(var + LN_EPS);
    const float4 g  = ((const float4*)gamma)[t];
    const float4 bt = ((const float4*)beta)[t];
    float4 o;
    o.x = (v.x - mu) * rstd * g.x + bt.x;
    o.y = (v.y - mu) * rstd * g.y + bt.y;
    o.z = (v.z - mu) * rstd * g.z + bt.z;
    o.w = (v.w - mu) * rstd * g.w + bt.w;
    ((float4*)(out + base))[t] = o;
}

// ------------- transpose + cast fp32 [R,C] -> fp16 [C,R] -------------------
__global__ __launch_bounds__(256)
void transpose_cast_kernel(const float* __restrict__ src,
                           f16* __restrict__ dst, int R, int C) {
    __shared__ float tile[32][33];
    const int c0 = blockIdx.x * 32, r0 = blockIdx.y * 32;
    const int tx = threadIdx.x & 31, ty = threadIdx.x >> 5;
    #pragma unroll
    for (int i = 0; i < 4; ++i) {
        const int r = ty + i * 8;
        tile[r][tx] = src[(size_t)(r0 + r) * C + c0 + tx];
    }
    __syncthreads();
    #pragma unroll
    for (int i = 0; i < 4; ++i) {
        const int r = ty + i * 8;
        dst[(size_t)(c0 + r) * R + r0 + tx] = (f16)tile[tx][r];
    }
}

// ------------- batched transpose fp16 [R,C] -> fp16 [C,R] ------------------
__global__ __launch_bounds__(256)
void transpose_f16_kernel(const f16* __restrict__ src,
                          f16* __restrict__ dst, int R, int C) {
    __shared__ f16 tile[32][33];
    const size_t zb = (size_t)blockIdx.z * R * C;
    src += zb; dst += zb;
    const int c0 = blockIdx.x * 32, r0 = blockIdx.y * 32;
    const int tx = threadIdx.x & 31, ty = threadIdx.x >> 5;
    #pragma unroll
    for (int i = 0; i < 4; ++i) {
        const int r = ty + i * 8;
        tile[r][tx] = src[(size_t)(r0 + r) * C + c0 + tx];
    }
    __syncthreads();
    #pragma unroll
    for (int i = 0; i < 4; ++i) {
        const int r = ty + i * 8;
        dst[(size_t)(c0 + r) * R + r0 + tx] = tile[tx][r];
    }
}

// ---------------- GEMM (NT): out[m][n] = sum_k A[m][k] * Bt[n][k] ----------
// 128x128 tile, BK=32, 4 waves (2x2), mfma_f32_16x16x32_f16.
// T3-minimum 2-phase: double-buffered LDS, STAGE(next) issued BEFORE
// ds_read+MFMA(cur), single barrier per K-step (barrier drains vmcnt+lgkmcnt).
// EPI: 0 = +bias, exact GELU, fp16 out [M][N]
//      1 = +bias, fp16 out TRANSPOSED per batch: out[z][col][row%2048] (T=2048)
//      2 = fp16 out [M][N] (batched)
//      3 = fp32 out + xadd (batched)
template <int EPI>
__global__ __launch_bounds__(256)
void gemm_nt_kernel(const f16* __restrict__ A, const f16* __restrict__ Bt,
                    const float* __restrict__ bias,
                    const float* __restrict__ xadd,
                    f16* __restrict__ outH, float* __restrict__ outF,
                    int M, int N, int K,
                    long long batchA, long long batchB, long long batchC) {
    __shared__ __attribute__((aligned(16))) f16 sA[2][128 * 32];
    __shared__ __attribute__((aligned(16))) f16 sB[2][128 * 32];

    const int z = blockIdx.z;
    A  += (size_t)z * batchA;
    Bt += (size_t)z * batchB;

    const int m0 = blockIdx.x * 128;
    const int n0 = blockIdx.y * 128;
    const int t = threadIdx.x;
    const int l = t & 63;
    const int wid = t >> 6;
    const int wm = (wid >> 1) * 64;
    const int wn = (wid & 1) * 64;

    f32x4 acc[4][4] = {};

    const int rl = l & 15;
    const int ko = (l >> 4) * 8;
    const int nk = K >> 5;

    // staging: chunk c = i*256 + t covers 16B at LDS byte c*16,
    // i.e. row = c>>2, k8 = (c&3)*8 of the [128][32] f16 tile.
    const int c0 = t, c1 = t + 256;
    const f16* Ag0 = A  + (size_t)(m0 + (c0 >> 2)) * K + (c0 & 3) * 8;
    const f16* Ag1 = A  + (size_t)(m0 + (c1 >> 2)) * K + (c1 & 3) * 8;
    const f16* Bg0 = Bt + (size_t)(n0 + (c0 >> 2)) * K + (c0 & 3) * 8;
    const f16* Bg1 = Bt + (size_t)(n0 + (c1 >> 2)) * K + (c1 & 3) * 8;
    // wave-uniform LDS chunk bases (HW adds lane*16B): wave w owns chunks
    // [w*64, w*64+64) and [256+w*64, ...) -> f16 offsets w*512 and 2048+w*512
    const int lo0 = wid * 512;
    const int lo1 = 2048 + wid * 512;

    // prologue: stage tile 0 into buf 0
    gload_lds16(Ag0, &sA[0][lo0]);
    gload_lds16(Ag1, &sA[0][lo1]);
    gload_lds16(Bg0, &sB[0][lo0]);
    gload_lds16(Bg1, &sB[0][lo1]);
    __syncthreads();   // drains vmcnt(0)+lgkmcnt(0)

    int cur = 0;
    for (int kt = 0; kt < nk; ++kt) {
        // 1) issue next-tile staging into the other buffer (in flight during MFMA)
        const int ktn = (kt + 1 < nk) ? kt + 1 : kt;   // redundant-safe tail
        const int kof = ktn * 32;
        f16* dA = sA[cur ^ 1];
        f16* dB = sB[cur ^ 1];
        gload_lds16(Ag0 + kof, dA + lo0);
        gload_lds16(Ag1 + kof, dA + lo1);
        gload_lds16(Bg0 + kof, dB + lo0);
        gload_lds16(Bg1 + kof, dB + lo1);

        // 2) compute current buffer
        const f16* rA = sA[cur];
        const f16* rB = sB[cur];
        f16x8 a[4], b[4];
        #pragma unroll
        for (int f = 0; f < 4; ++f) {
            a[f] = *(const f16x8*)&rA[(wm + f * 16 + rl) * 32 + ko];
            b[f] = *(const f16x8*)&rB[(wn + f * 16 + rl) * 32 + ko];
        }
        #pragma unroll
        for (int fm = 0; fm < 4; ++fm)
            #pragma unroll
            for (int fn = 0; fn < 4; ++fn)
                acc[fm][fn] = __builtin_amdgcn_mfma_f32_16x16x32_f16(
                    a[fm], b[fn], acc[fm][fn], 0, 0, 0);

        // 3) single barrier: drains staging (vmcnt) + our ds_reads (lgkmcnt)
        __syncthreads();
        cur ^= 1;
    }

    // epilogue: D mapping col = l&15, row = (l>>4)*4 + r
    const int rh = l >> 4;
    const float* xaddz = xadd;
    f16* outHz = outH;
    float* outFz = outF;
    if (EPI == 3) {
        outFz += (size_t)z * batchC;
        xaddz += (size_t)z * batchC;
    } else if (EPI == 2) {
        outHz += (size_t)z * batchC;
    }
    #pragma unroll
    for (int fm = 0; fm < 4; ++fm) {
        #pragma unroll
        for (int fn = 0; fn < 4; ++fn) {
            const int col = n0 + wn + fn * 16 + rl;
            if (EPI == 1) {
                // transposed-per-batch write: rows r=0..3 consecutive along T
                const int row0 = m0 + wm + fm * 16 + rh * 4;
                const int zz = row0 >> 11;
                const int rr = row0 & 2047;
                const float bv = bias[col];
                f16x4 o;
                #pragma unroll
                for (int r = 0; r < 4; ++r) o[r] = (f16)(acc[fm][fn][r] + bv);
                *(f16x4*)(outH + ((size_t)zz * N + col) * 2048 + rr) = o;
            } else {
                #pragma unroll
                for (int r = 0; r < 4; ++r) {
                    const int row = m0 + wm + fm * 16 + rh * 4 + r;
                    float v = acc[fm][fn][r];
                    const size_t idx = (size_t)row * N + col;
                    if (EPI == 0) {
                        v += bias[col];
                        outHz[idx] = (f16)gelu_exact(v);
                    } else if (EPI == 2) {
                        outHz[idx] = (f16)v;
                    } else {
                        outFz[idx] = v + xaddz[idx];
                    }
                }
            }
        }
    }
}

extern "C" void kernel_launch(void* const* d_in, const int* in_sizes, int n_in,
                              void* d_out, int out_size, void* d_ws, size_t ws_size,
                              hipStream_t stream) {
    const float* x     = (const float*)d_in[0];
    const float* gamma = (const float*)d_in[1];
    const float* beta  = (const float*)d_in[2];
    const float* w1    = (const float*)d_in[3];
    const float* b1    = (const float*)d_in[4];
    const float* w2    = (const float*)d_in[5];
    const float* b2    = (const float*)d_in[6];
    float* out = (float*)d_out;

    const int BS = 4, T = 2048, DIM = 1024, HID = 2048;
    const int M = BS * T;  // 8192
    const long long MB = 1024 * 1024;

    // workspace layout (112 MiB total)
    char* ws = (char*)d_ws;
    f16*   x_h  = (f16*)(ws + 0 * MB);    // 16 MiB [M][DIM]
    f16*   y_h  = (f16*)(ws + 16 * MB);   // 16 MiB [M][DIM]
    f16*   h    = (f16*)(ws + 32 * MB);   // 32 MiB [M][HID]
    float* pre  = (float*)h;              // alias: h dead after GEMM2
    f16*   y2t  = (f16*)(ws + 64 * MB);   // 16 MiB [BS][DIM][T]
    f16*   x_t  = (f16*)(ws + 80 * MB);   // 16 MiB [BS][DIM][T]
    f16*   G    = (f16*)(ws + 96 * MB);   // 8 MiB  [BS][DIM][DIM]  (G' = y2^T x per batch)
    f16*   w1t  = (f16*)(ws + 104 * MB);  // 4 MiB  [HID][DIM]
    f16*   w2t  = (f16*)(ws + 108 * MB);  // 4 MiB  [DIM][HID]

    // 1) first LN + fp16 casts
    ln_cast_kernel<<<M, 256, 0, stream>>>(x, gamma, beta, y_h, x_h);

    // 2) weight transposes to fp16 [N][K]
    transpose_cast_kernel<<<dim3(HID / 32, DIM / 32), 256, 0, stream>>>(w1, w1t, DIM, HID);
    transpose_cast_kernel<<<dim3(DIM / 32, HID / 32), 256, 0, stream>>>(w2, w2t, HID, DIM);

    // 3) h = gelu(y @ w1 + b1)   [M][HID]
    gemm_nt_kernel<0><<<dim3(M / 128, HID / 128, 1), 256, 0, stream>>>(
        y_h, w1t, b1, nullptr, h, nullptr, M, HID, DIM, 0, 0, 0);

    // 4) y2t[z][f][t] = (h @ w2 + b2)[z*T+t][f]   (transposed epilogue)
    gemm_nt_kernel<1><<<dim3(M / 128, DIM / 128, 1), 256, 0, stream>>>(
        h, w2t, b2, nullptr, y2t, nullptr, M, DIM, HID, 0, 0, 0);

    // 5) x_t[z][f][t] = x_h[z*T+t][f]
    transpose_f16_kernel<<<dim3(DIM / 32, T / 32, BS), 256, 0, stream>>>(x_h, x_t, T, DIM);

    // 6) G'[z][f2][f1] = sum_t y2t[z][f2][t] * x_t[z][f1][t]   ( = (x^T y2)^T )
    gemm_nt_kernel<2><<<dim3(DIM / 128, DIM / 128, BS), 256, 0, stream>>>(
        y2t, x_t, nullptr, nullptr, G, nullptr, DIM, DIM, T,
        (long long)DIM * T, (long long)DIM * T, (long long)DIM * DIM);

    // 7) pre[z][t][f] = sum_k x_h[z][t][k] * G'[z][f][k] + x   (= x (x^T y2) + x)
    gemm_nt_kernel<3><<<dim3(T / 128, DIM / 128, BS), 256, 0, stream>>>(
        x_h, G, nullptr, x, nullptr, pre, T, DIM, DIM,
        (long long)T * DIM, (long long)DIM * DIM, (long long)T * DIM);

    // 8) final LN
    ln_final_kernel<<<M, 256, 0, stream>>>(pre, gamma, beta, out);
}

// Round 4
// 226.203 us; speedup vs baseline: 1.3431x; 1.0808x over previous
//
#include <hip/hip_runtime.h>
#include <hip/hip_fp16.h>

typedef _Float16 f16;
typedef _Float16 f16x8 __attribute__((ext_vector_type(8)));
typedef _Float16 f16x4 __attribute__((ext_vector_type(4)));
typedef float f32x4 __attribute__((ext_vector_type(4)));

#define LN_EPS 1e-5f

// erf via Abramowitz-Stegun 7.1.26 (|eps| <= 1.5e-7)
__device__ __forceinline__ float erf_fast(float x) {
    const float ax = __builtin_fabsf(x);
    const float t = 1.0f / (1.0f + 0.3275911f * ax);
    const float y = t * (0.254829592f +
                    t * (-0.284496736f +
                    t * (1.421413741f +
                    t * (-1.453152027f +
                    t * 1.061405429f))));
    const float r = 1.0f - y * __expf(-ax * ax);
    return __builtin_copysignf(r, x);
}

__device__ __forceinline__ float gelu_exact(float v) {
    return 0.5f * v * (1.0f + erf_fast(v * 0.70710678118654752440f));
}

// async global -> LDS, 16B per lane; lds dest is wave-uniform base (+lane*16 by HW)
__device__ __forceinline__ void gload_lds16(const f16* g, f16* l) {
    __builtin_amdgcn_global_load_lds(
        (const __attribute__((address_space(1))) unsigned int*)(g),
        (__attribute__((address_space(3))) unsigned int*)(l),
        16, 0, 0);
}

// ---------------- LayerNorm(x) -> y_h (fp16), plus x -> x_h (fp16) ----------
__global__ __launch_bounds__(256)
void ln_cast_kernel(const float* __restrict__ x,
                    const float* __restrict__ gamma,
                    const float* __restrict__ beta,
                    f16* __restrict__ y_h,
                    f16* __restrict__ x_h) {
    const int row = blockIdx.x;
    const int t = threadIdx.x;
    const size_t base = (size_t)row * 1024;
    float4 v = ((const float4*)(x + base))[t];
    float s  = v.x + v.y + v.z + v.w;
    float s2 = v.x*v.x + v.y*v.y + v.z*v.z + v.w*v.w;
    #pragma unroll
    for (int off = 32; off > 0; off >>= 1) {
        s  += __shfl_down(s, off, 64);
        s2 += __shfl_down(s2, off, 64);
    }
    __shared__ float ls[4], ls2[4];
    const int wid = t >> 6;
    if ((t & 63) == 0) { ls[wid] = s; ls2[wid] = s2; }
    __syncthreads();
    if (t == 0) {
        ls[0]  = ls[0] + ls[1] + ls[2] + ls[3];
        ls2[0] = ls2[0] + ls2[1] + ls2[2] + ls2[3];
    }
    __syncthreads();
    const float mu   = ls[0] * (1.0f / 1024.0f);
    const float var  = ls2[0] * (1.0f / 1024.0f) - mu * mu;
    const float rstd = rsqrtf(var + LN_EPS);
    const float4 g  = ((const float4*)gamma)[t];
    const float4 bt = ((const float4*)beta)[t];
    f16x4 yo, xo;
    yo[0] = (f16)((v.x - mu) * rstd * g.x + bt.x);
    yo[1] = (f16)((v.y - mu) * rstd * g.y + bt.y);
    yo[2] = (f16)((v.z - mu) * rstd * g.z + bt.z);
    yo[3] = (f16)((v.w - mu) * rstd * g.w + bt.w);
    xo[0] = (f16)v.x; xo[1] = (f16)v.y; xo[2] = (f16)v.z; xo[3] = (f16)v.w;
    *(f16x4*)(y_h + base + t * 4) = yo;
    *(f16x4*)(x_h + base + t * 4) = xo;
}

// ---------------- final LayerNorm: pre (fp32) -> out (fp32) ----------------
__global__ __launch_bounds__(256)
void ln_final_kernel(const float* __restrict__ pre,
                     const float* __restrict__ gamma,
                     const float* __restrict__ beta,
                     float* __restrict__ out) {
    const int row = blockIdx.x;
    const int t = threadIdx.x;
    const size_t base = (size_t)row * 1024;
    float4 v = ((const float4*)(pre + base))[t];
    float s  = v.x + v.y + v.z + v.w;
    float s2 = v.x*v.x + v.y*v.y + v.z*v.z + v.w*v.w;
    #pragma unroll
    for (int off = 32; off > 0; off >>= 1) {
        s  += __shfl_down(s, off, 64);
        s2 += __shfl_down(s2, off, 64);
    }
    __shared__ float ls[4], ls2[4];
    const int wid = t >> 6;
    if ((t & 63) == 0) { ls[wid] = s; ls2[wid] = s2; }
    __syncthreads();
    if (t == 0) {
        ls[0]  = ls[0] + ls[1] + ls[2] + ls[3];
        ls2[0] = ls2[0] + ls2[1] + ls2[2] + ls2[3];
    }
    __syncthreads();
    const float mu   = ls[0] * (1.0f / 1024.0f);
    const float var  = ls2[0] * (1.0f / 1024.0f) - mu * mu;
    const float rstd = rsqrtf(var + LN_EPS);
    const float4 g  = ((const float4*)gamma)[t];
    const float4 bt = ((const float4*)beta)[t];
    float4 o;
    o.x = (v.x - mu) * rstd * g.x + bt.x;
    o.y = (v.y - mu) * rstd * g.y + bt.y;
    o.z = (v.z - mu) * rstd * g.z + bt.z;
    o.w = (v.w - mu) * rstd * g.w + bt.w;
    ((float4*)(out + base))[t] = o;
}

// ------------- transpose + cast fp32 [R,C] -> fp16 [C,R] -------------------
__global__ __launch_bounds__(256)
void transpose_cast_kernel(const float* __restrict__ src,
                           f16* __restrict__ dst, int R, int C) {
    __shared__ float tile[32][33];
    const int c0 = blockIdx.x * 32, r0 = blockIdx.y * 32;
    const int tx = threadIdx.x & 31, ty = threadIdx.x >> 5;
    #pragma unroll
    for (int i = 0; i < 4; ++i) {
        const int r = ty + i * 8;
        tile[r][tx] = src[(size_t)(r0 + r) * C + c0 + tx];
    }
    __syncthreads();
    #pragma unroll
    for (int i = 0; i < 4; ++i) {
        const int r = ty + i * 8;
        dst[(size_t)(c0 + r) * R + r0 + tx] = (f16)tile[tx][r];
    }
}

// ------------- batched transpose fp16 [R,C] -> fp16 [C,R] ------------------
__global__ __launch_bounds__(256)
void transpose_f16_kernel(const f16* __restrict__ src,
                          f16* __restrict__ dst, int R, int C) {
    __shared__ f16 tile[32][33];
    const size_t zb = (size_t)blockIdx.z * R * C;
    src += zb; dst += zb;
    const int c0 = blockIdx.x * 32, r0 = blockIdx.y * 32;
    const int tx = threadIdx.x & 31, ty = threadIdx.x >> 5;
    #pragma unroll
    for (int i = 0; i < 4; ++i) {
        const int r = ty + i * 8;
        tile[r][tx] = src[(size_t)(r0 + r) * C + c0 + tx];
    }
    __syncthreads();
    #pragma unroll
    for (int i = 0; i < 4; ++i) {
        const int r = ty + i * 8;
        dst[(size_t)(c0 + r) * R + r0 + tx] = tile[tx][r];
    }
}

// ---------------- GEMM (NT): out[m][n] = sum_k A[m][k] * Bt[n][k] ----------
// 128x128 tile, BK=32, 4 waves (2x2), mfma_f32_16x16x32_f16.
// T3+T4: ring-3 LDS (48 KiB, 3 blocks/CU), prefetch tile k+2.
// Per iter: vmcnt(4) [tile k landed; k+1,k+2 stay in flight] -> s_barrier ->
// issue STAGE(k+2) -> ds_read(k) -> MFMA. vmcnt never drained to 0 in-loop.
// Overwrite safety: slot(k+2) == slot(k-1); its reads completed before each
// wave's barrier-k arrival (lgkmcnt precedes the MFMAs that precede the
// barrier in program order) -> barrier-ordered, not timing-dependent.
// EPI: 0 = +bias, exact GELU, fp16 out [M][N]
//      1 = +bias, fp16 out TRANSPOSED per batch: out[z][col][row%2048] (T=2048)
//      2 = fp16 out [M][N] (batched)
//      3 = fp32 out + xadd (batched)
template <int EPI>
__global__ __launch_bounds__(256, 3)
void gemm_nt_kernel(const f16* __restrict__ A, const f16* __restrict__ Bt,
                    const float* __restrict__ bias,
                    const float* __restrict__ xadd,
                    f16* __restrict__ outH, float* __restrict__ outF,
                    int M, int N, int K,
                    long long batchA, long long batchB, long long batchC) {
    __shared__ __attribute__((aligned(16))) f16 sA[3][128 * 32];
    __shared__ __attribute__((aligned(16))) f16 sB[3][128 * 32];

    const int z = blockIdx.z;
    A  += (size_t)z * batchA;
    Bt += (size_t)z * batchB;

    const int m0 = blockIdx.x * 128;
    const int n0 = blockIdx.y * 128;
    const int t = threadIdx.x;
    const int l = t & 63;
    const int wid = t >> 6;
    const int wm = (wid >> 1) * 64;
    const int wn = (wid & 1) * 64;

    f32x4 acc[4][4] = {};

    const int rl = l & 15;
    const int ko = (l >> 4) * 8;
    const int nk = K >> 5;   // >= 32 for all our shapes

    // staging: chunk c = i*256 + t covers 16B at LDS byte c*16,
    // i.e. row = c>>2, k8 = (c&3)*8 of the [128][32] f16 tile.
    const int c0 = t, c1 = t + 256;
    const f16* Ag0 = A  + (size_t)(m0 + (c0 >> 2)) * K + (c0 & 3) * 8;
    const f16* Ag1 = A  + (size_t)(m0 + (c1 >> 2)) * K + (c1 & 3) * 8;
    const f16* Bg0 = Bt + (size_t)(n0 + (c0 >> 2)) * K + (c0 & 3) * 8;
    const f16* Bg1 = Bt + (size_t)(n0 + (c1 >> 2)) * K + (c1 & 3) * 8;
    // wave-uniform LDS chunk bases (HW adds lane*16B)
    const int lo0 = wid * 512;
    const int lo1 = 2048 + wid * 512;

    // prologue: stage tiles 0 and 1 into ring slots 0,1 (8 loads in flight)
    gload_lds16(Ag0,      sA[0] + lo0);
    gload_lds16(Ag1,      sA[0] + lo1);
    gload_lds16(Bg0,      sB[0] + lo0);
    gload_lds16(Bg1,      sB[0] + lo1);
    gload_lds16(Ag0 + 32, sA[1] + lo0);
    gload_lds16(Ag1 + 32, sA[1] + lo1);
    gload_lds16(Bg0 + 32, sB[1] + lo0);
    gload_lds16(Bg1 + 32, sB[1] + lo1);

    f16 *curA = sA[0], *nxtA = sA[1], *farA = sA[2];
    f16 *curB = sB[0], *nxtB = sB[1], *farB = sB[2];

    for (int kt = 0; kt < nk; ++kt) {
        // tile k landed for THIS wave (newest 4 outstanding = tile k+1)
        asm volatile("s_waitcnt vmcnt(4)" ::: "memory");
        // all waves: tile k landed; all reads of slot(k-1) completed
        __builtin_amdgcn_s_barrier();

        // issue prefetch of tile k+2 into slot(k-1) (clamped tail keeps the
        // vmcnt count exact; redundant data is never read)
        const int ktn = (kt + 2 < nk) ? kt + 2 : nk - 1;
        const int kof = ktn * 32;
        gload_lds16(Ag0 + kof, farA + lo0);
        gload_lds16(Ag1 + kof, farA + lo1);
        gload_lds16(Bg0 + kof, farB + lo0);
        gload_lds16(Bg1 + kof, farB + lo1);

        // compute tile k from slot cur
        f16x8 a[4], b[4];
        #pragma unroll
        for (int f = 0; f < 4; ++f) {
            a[f] = *(const f16x8*)&curA[(wm + f * 16 + rl) * 32 + ko];
            b[f] = *(const f16x8*)&curB[(wn + f * 16 + rl) * 32 + ko];
        }
        #pragma unroll
        for (int fm = 0; fm < 4; ++fm)
            #pragma unroll
            for (int fn = 0; fn < 4; ++fn)
                acc[fm][fn] = __builtin_amdgcn_mfma_f32_16x16x32_f16(
                    a[fm], b[fn], acc[fm][fn], 0, 0, 0);

        // rotate ring
        f16* tA = curA; curA = nxtA; nxtA = farA; farA = tA;
        f16* tB = curB; curB = nxtB; nxtB = farB; farB = tB;
    }
    // hygiene: drain remaining prefetches before the wave exits
    asm volatile("s_waitcnt vmcnt(0)" ::: "memory");

    // epilogue: D mapping col = l&15, row = (l>>4)*4 + r
    const int rh = l >> 4;
    const float* xaddz = xadd;
    f16* outHz = outH;
    float* outFz = outF;
    if (EPI == 3) {
        outFz += (size_t)z * batchC;
        xaddz += (size_t)z * batchC;
    } else if (EPI == 2) {
        outHz += (size_t)z * batchC;
    }
    #pragma unroll
    for (int fm = 0; fm < 4; ++fm) {
        #pragma unroll
        for (int fn = 0; fn < 4; ++fn) {
            const int col = n0 + wn + fn * 16 + rl;
            if (EPI == 1) {
                // transposed-per-batch write: rows r=0..3 consecutive along T
                const int row0 = m0 + wm + fm * 16 + rh * 4;
                const int zz = row0 >> 11;
                const int rr = row0 & 2047;
                const float bv = bias[col];
                f16x4 o;
                #pragma unroll
                for (int r = 0; r < 4; ++r) o[r] = (f16)(acc[fm][fn][r] + bv);
                *(f16x4*)(outH + ((size_t)zz * N + col) * 2048 + rr) = o;
            } else {
                #pragma unroll
                for (int r = 0; r < 4; ++r) {
                    const int row = m0 + wm + fm * 16 + rh * 4 + r;
                    float v = acc[fm][fn][r];
                    const size_t idx = (size_t)row * N + col;
                    if (EPI == 0) {
                        v += bias[col];
                        outHz[idx] = (f16)gelu_exact(v);
                    } else if (EPI == 2) {
                        outHz[idx] = (f16)v;
                    } else {
                        outFz[idx] = v + xaddz[idx];
                    }
                }
            }
        }
    }
}

extern "C" void kernel_launch(void* const* d_in, const int* in_sizes, int n_in,
                              void* d_out, int out_size, void* d_ws, size_t ws_size,
                              hipStream_t stream) {
    const float* x     = (const float*)d_in[0];
    const float* gamma = (const float*)d_in[1];
    const float* beta  = (const float*)d_in[2];
    const float* w1    = (const float*)d_in[3];
    const float* b1    = (const float*)d_in[4];
    const float* w2    = (const float*)d_in[5];
    const float* b2    = (const float*)d_in[6];
    float* out = (float*)d_out;

    const int BS = 4, T = 2048, DIM = 1024, HID = 2048;
    const int M = BS * T;  // 8192
    const long long MB = 1024 * 1024;

    // workspace layout (112 MiB total)
    char* ws = (char*)d_ws;
    f16*   x_h  = (f16*)(ws + 0 * MB);    // 16 MiB [M][DIM]
    f16*   y_h  = (f16*)(ws + 16 * MB);   // 16 MiB [M][DIM]
    f16*   h    = (f16*)(ws + 32 * MB);   // 32 MiB [M][HID]
    float* pre  = (float*)h;              // alias: h dead after GEMM2
    f16*   y2t  = (f16*)(ws + 64 * MB);   // 16 MiB [BS][DIM][T]
    f16*   x_t  = (f16*)(ws + 80 * MB);   // 16 MiB [BS][DIM][T]
    f16*   G    = (f16*)(ws + 96 * MB);   // 8 MiB  [BS][DIM][DIM]  (G' = y2^T x per batch)
    f16*   w1t  = (f16*)(ws + 104 * MB);  // 4 MiB  [HID][DIM]
    f16*   w2t  = (f16*)(ws + 108 * MB);  // 4 MiB  [DIM][HID]

    // 1) first LN + fp16 casts
    ln_cast_kernel<<<M, 256, 0, stream>>>(x, gamma, beta, y_h, x_h);

    // 2) weight transposes to fp16 [N][K]
    transpose_cast_kernel<<<dim3(HID / 32, DIM / 32), 256, 0, stream>>>(w1, w1t, DIM, HID);
    transpose_cast_kernel<<<dim3(DIM / 32, HID / 32), 256, 0, stream>>>(w2, w2t, HID, DIM);

    // 3) h = gelu(y @ w1 + b1)   [M][HID]
    gemm_nt_kernel<0><<<dim3(M / 128, HID / 128, 1), 256, 0, stream>>>(
        y_h, w1t, b1, nullptr, h, nullptr, M, HID, DIM, 0, 0, 0);

    // 4) y2t[z][f][t] = (h @ w2 + b2)[z*T+t][f]   (transposed epilogue)
    gemm_nt_kernel<1><<<dim3(M / 128, DIM / 128, 1), 256, 0, stream>>>(
        h, w2t, b2, nullptr, y2t, nullptr, M, DIM, HID, 0, 0, 0);

    // 5) x_t[z][f][t] = x_h[z*T+t][f]
    transpose_f16_kernel<<<dim3(DIM / 32, T / 32, BS), 256, 0, stream>>>(x_h, x_t, T, DIM);

    // 6) G'[z][f2][f1] = sum_t y2t[z][f2][t] * x_t[z][f1][t]   ( = (x^T y2)^T )
    gemm_nt_kernel<2><<<dim3(DIM / 128, DIM / 128, BS), 256, 0, stream>>>(
        y2t, x_t, nullptr, nullptr, G, nullptr, DIM, DIM, T,
        (long long)DIM * T, (long long)DIM * T, (long long)DIM * DIM);

    // 7) pre[z][t][f] = sum_k x_h[z][t][k] * G'[z][f][k] + x   (= x (x^T y2) + x)
    gemm_nt_kernel<3><<<dim3(T / 128, DIM / 128, BS), 256, 0, stream>>>(
        x_h, G, nullptr, x, nullptr, pre, T, DIM, DIM,
        (long long)T * DIM, (long long)DIM * DIM, (long long)T * DIM);

    // 8) final LN
    ln_final_kernel<<<M, 256, 0, stream>>>(pre, gamma, beta, out);
}

// Round 5
// 212.220 us; speedup vs baseline: 1.4316x; 1.0659x over previous
//
#include <hip/hip_runtime.h>
#include <hip/hip_fp16.h>

typedef _Float16 f16;
typedef _Float16 f16x8 __attribute__((ext_vector_type(8)));
typedef _Float16 f16x4 __attribute__((ext_vector_type(4)));
typedef float f32x4 __attribute__((ext_vector_type(4)));

#define LN_EPS 1e-5f

// erf via Abramowitz-Stegun 7.1.26 (|eps| <= 1.5e-7)
__device__ __forceinline__ float erf_fast(float x) {
    const float ax = __builtin_fabsf(x);
    const float t = 1.0f / (1.0f + 0.3275911f * ax);
    const float y = t * (0.254829592f +
                    t * (-0.284496736f +
                    t * (1.421413741f +
                    t * (-1.453152027f +
                    t * 1.061405429f))));
    const float r = 1.0f - y * __expf(-ax * ax);
    return __builtin_copysignf(r, x);
}

__device__ __forceinline__ float gelu_exact(float v) {
    return 0.5f * v * (1.0f + erf_fast(v * 0.70710678118654752440f));
}

// async global -> LDS, 16B per lane; lds dest is wave-uniform base (+lane*16 by HW)
__device__ __forceinline__ void gload_lds16(const f16* g, f16* l) {
    __builtin_amdgcn_global_load_lds(
        (const __attribute__((address_space(1))) unsigned int*)(g),
        (__attribute__((address_space(3))) unsigned int*)(l),
        16, 0, 0);
}

// ---------------- LayerNorm(x) -> y_h (fp16), plus x -> x_h (fp16) ----------
__global__ __launch_bounds__(256)
void ln_cast_kernel(const float* __restrict__ x,
                    const float* __restrict__ gamma,
                    const float* __restrict__ beta,
                    f16* __restrict__ y_h,
                    f16* __restrict__ x_h) {
    const int row = blockIdx.x;
    const int t = threadIdx.x;
    const size_t base = (size_t)row * 1024;
    float4 v = ((const float4*)(x + base))[t];
    float s  = v.x + v.y + v.z + v.w;
    float s2 = v.x*v.x + v.y*v.y + v.z*v.z + v.w*v.w;
    #pragma unroll
    for (int off = 32; off > 0; off >>= 1) {
        s  += __shfl_down(s, off, 64);
        s2 += __shfl_down(s2, off, 64);
    }
    __shared__ float ls[4], ls2[4];
    const int wid = t >> 6;
    if ((t & 63) == 0) { ls[wid] = s; ls2[wid] = s2; }
    __syncthreads();
    if (t == 0) {
        ls[0]  = ls[0] + ls[1] + ls[2] + ls[3];
        ls2[0] = ls2[0] + ls2[1] + ls2[2] + ls2[3];
    }
    __syncthreads();
    const float mu   = ls[0] * (1.0f / 1024.0f);
    const float var  = ls2[0] * (1.0f / 1024.0f) - mu * mu;
    const float rstd = rsqrtf(var + LN_EPS);
    const float4 g  = ((const float4*)gamma)[t];
    const float4 bt = ((const float4*)beta)[t];
    f16x4 yo, xo;
    yo[0] = (f16)((v.x - mu) * rstd * g.x + bt.x);
    yo[1] = (f16)((v.y - mu) * rstd * g.y + bt.y);
    yo[2] = (f16)((v.z - mu) * rstd * g.z + bt.z);
    yo[3] = (f16)((v.w - mu) * rstd * g.w + bt.w);
    xo[0] = (f16)v.x; xo[1] = (f16)v.y; xo[2] = (f16)v.z; xo[3] = (f16)v.w;
    *(f16x4*)(y_h + base + t * 4) = yo;
    *(f16x4*)(x_h + base + t * 4) = xo;
}

// ---------------- final LayerNorm: pre (fp32) -> out (fp32) ----------------
__global__ __launch_bounds__(256)
void ln_final_kernel(const float* __restrict__ pre,
                     const float* __restrict__ gamma,
                     const float* __restrict__ beta,
                     float* __restrict__ out) {
    const int row = blockIdx.x;
    const int t = threadIdx.x;
    const size_t base = (size_t)row * 1024;
    float4 v = ((const float4*)(pre + base))[t];
    float s  = v.x + v.y + v.z + v.w;
    float s2 = v.x*v.x + v.y*v.y + v.z*v.z + v.w*v.w;
    #pragma unroll
    for (int off = 32; off > 0; off >>= 1) {
        s  += __shfl_down(s, off, 64);
        s2 += __shfl_down(s2, off, 64);
    }
    __shared__ float ls[4], ls2[4];
    const int wid = t >> 6;
    if ((t & 63) == 0) { ls[wid] = s; ls2[wid] = s2; }
    __syncthreads();
    if (t == 0) {
        ls[0]  = ls[0] + ls[1] + ls[2] + ls[3];
        ls2[0] = ls2[0] + ls2[1] + ls2[2] + ls2[3];
    }
    __syncthreads();
    const float mu   = ls[0] * (1.0f / 1024.0f);
    const float var  = ls2[0] * (1.0f / 1024.0f) - mu * mu;
    const float rstd = rsqrtf(var + LN_EPS);
    const float4 g  = ((const float4*)gamma)[t];
    const float4 bt = ((const float4*)beta)[t];
    float4 o;
    o.x = (v.x - mu) * rstd * g.x + bt.x;
    o.y = (v.y - mu) * rstd * g.y + bt.y;
    o.z = (v.z - mu) * rstd * g.z + bt.z;
    o.w = (v.w - mu) * rstd * g.w + bt.w;
    ((float4*)(out + base))[t] = o;
}

// ------------- transpose + cast fp32 [R,C] -> fp16 [C,R] -------------------
__global__ __launch_bounds__(256)
void transpose_cast_kernel(const float* __restrict__ src,
                           f16* __restrict__ dst, int R, int C) {
    __shared__ float tile[32][33];
    const int c0 = blockIdx.x * 32, r0 = blockIdx.y * 32;
    const int tx = threadIdx.x & 31, ty = threadIdx.x >> 5;
    #pragma unroll
    for (int i = 0; i < 4; ++i) {
        const int r = ty + i * 8;
        tile[r][tx] = src[(size_t)(r0 + r) * C + c0 + tx];
    }
    __syncthreads();
    #pragma unroll
    for (int i = 0; i < 4; ++i) {
        const int r = ty + i * 8;
        dst[(size_t)(c0 + r) * R + r0 + tx] = (f16)tile[tx][r];
    }
}

// ------------- batched transpose fp16 [R,C] -> fp16 [C,R] ------------------
__global__ __launch_bounds__(256)
void transpose_f16_kernel(const f16* __restrict__ src,
                          f16* __restrict__ dst, int R, int C) {
    __shared__ f16 tile[32][33];
    const size_t zb = (size_t)blockIdx.z * R * C;
    src += zb; dst += zb;
    const int c0 = blockIdx.x * 32, r0 = blockIdx.y * 32;
    const int tx = threadIdx.x & 31, ty = threadIdx.x >> 5;
    #pragma unroll
    for (int i = 0; i < 4; ++i) {
        const int r = ty + i * 8;
        tile[r][tx] = src[(size_t)(r0 + r) * C + c0 + tx];
    }
    __syncthreads();
    #pragma unroll
    for (int i = 0; i < 4; ++i) {
        const int r = ty + i * 8;
        dst[(size_t)(c0 + r) * R + r0 + tx] = tile[tx][r];
    }
}

// ============ 256x256 8-wave GEMM (NT), BK=64, 8-phase, T2+T3+T4+T5 ========
// out[m][n] = gelu(sum_k A[m][k]*Bt[n][k] + bias[n]) as fp16.
// LDS [256][64] f16 per op per buf (128 KiB total). Swizzle: 16B slot s of
// row r holds k-slot s^(r&7); staged via pre-swizzled GLOBAL source (LDS
// writes linear), read with slot = q^(r&7). Wave (wr,wc): 2x4, tile 128x64.
// Phases per K-tile: P0 {rd a[fm0-3],b0; stg A1(kt+1)->o; MFMA q0xh0}
//                    P1 {rd b1;                          MFMA q0xh1}
//                    P2 {rd a[fm4-7]; stg B0(kt+2)->c;   MFMA q1xh1}
//                    P3 {stg B1,A0(kt+2)->c; MFMA q1xh0; vmcnt(6)}
// Region safety (barrier-counted): B-halves of c fully read after P1,
// A-halves after P2; tile kt+2 parity == c. Steady outstanding = 6 loads
// {B0,B1,A0 of kt+1} at each tile boundary -> vmcnt(6), never drained.
template <int EPI>
__global__ __launch_bounds__(512, 2)
void gemm256_nt_kernel(const f16* __restrict__ A, const f16* __restrict__ Bt,
                       const float* __restrict__ bias, f16* __restrict__ outH,
                       int M, int N, int K) {
    __shared__ __attribute__((aligned(16))) f16 sAbuf[2][256 * 64];
    __shared__ __attribute__((aligned(16))) f16 sBbuf[2][256 * 64];

    const int m0 = blockIdx.x * 256;
    const int n0 = blockIdx.y * 256;
    const int t = threadIdx.x;
    const int l = t & 63;
    const int wid = t >> 6;
    const int wr = wid >> 2;      // 0-1
    const int wc = wid & 3;       // 0-3
    const int rl = l & 15;
    const int g  = l >> 4;        // 0-3
    const int nk = K >> 6;

    // staging per-lane constants: chunk c = wid*128 + j*64 + l
    // row = wid*16 + (l>>3) (+8 for j=1), slot = l&7,
    // source k-slot = slot ^ (row&7)  (row&7 == (l>>3)&7 for both j)
    const int rowS = wid * 16 + (l >> 3);
    const int kbS  = ((l & 7) ^ ((l >> 3) & 7)) * 8;
    const f16* pA = A  + (size_t)(m0 + rowS) * K + kbS;
    const f16* pB = Bt + (size_t)(n0 + rowS) * K + kbS;
    const int ldsS = wid * 1024;   // f16 offset of wave's region within a half

    // ds_read per-lane constants
    const int rA = wr * 128 + rl;
    const int rB = wc * 64 + rl;
    const int swk0 = ((g)     ^ (rl & 7)) * 8;   // k-slice 0
    const int swk1 = ((4 + g) ^ (rl & 7)) * 8;   // k-slice 1

    f32x4 acc[8][4] = {};

    const long long hstep = (long long)128 * K;

    auto stgA = [&](f16* dst, int h, int kc) {
        const f16* s = pA + (size_t)h * hstep + kc * 64;
        f16* d = dst + h * 8192 + ldsS;
        gload_lds16(s, d);
        gload_lds16(s + 8 * K, d + 512);
    };
    auto stgB = [&](f16* dst, int h, int kc) {
        const f16* s = pB + (size_t)h * hstep + kc * 64;
        f16* d = dst + h * 8192 + ldsS;
        gload_lds16(s, d);
        gload_lds16(s + 8 * K, d + 512);
    };

    f16* bufA0 = sAbuf[0]; f16* bufA1 = sAbuf[1];
    f16* bufB0 = sBbuf[0]; f16* bufB1 = sBbuf[1];

    // prologue: tile0 fully, then B0,B1,A0 of tile1 LAST (these 6 stay in flight)
    const int t1 = (nk > 1) ? 1 : 0;
    stgA(bufA0, 0, 0); stgA(bufA0, 1, 0);
    stgB(bufB0, 0, 0); stgB(bufB0, 1, 0);
    stgB(bufB1, 0, t1); stgB(bufB1, 1, t1);
    stgA(bufA1, 0, t1);
    asm volatile("s_waitcnt vmcnt(6)" ::: "memory");
    __builtin_amdgcn_s_barrier();

    f16 *Ac = bufA0, *Ao = bufA1, *Bc = bufB0, *Bo = bufB1;

    f16x8 a[4][2], b0r[2][2], b1r[2][2];

    for (int kt = 0; kt < nk; ++kt) {
        const int kt1 = (kt + 1 < nk) ? kt + 1 : nk - 1;
        const int kt2 = (kt + 2 < nk) ? kt + 2 : nk - 1;

        // ---------------- P0 ----------------
        #pragma unroll
        for (int fm = 0; fm < 4; ++fm) {
            a[fm][0] = *(const f16x8*)(Ac + (rA + fm * 16) * 64 + swk0);
            a[fm][1] = *(const f16x8*)(Ac + (rA + fm * 16) * 64 + swk1);
        }
        #pragma unroll
        for (int fn = 0; fn < 2; ++fn) {
            b0r[fn][0] = *(const f16x8*)(Bc + (rB + fn * 16) * 64 + swk0);
            b0r[fn][1] = *(const f16x8*)(Bc + (rB + fn * 16) * 64 + swk1);
        }
        stgA(Ao, 1, kt1);
        __builtin_amdgcn_s_barrier();
        asm volatile("s_waitcnt lgkmcnt(0)" ::: "memory");
        __builtin_amdgcn_sched_barrier(0);
        __builtin_amdgcn_s_setprio(1);
        #pragma unroll
        for (int fm = 0; fm < 4; ++fm)
            #pragma unroll
            for (int fn = 0; fn < 2; ++fn) {
                acc[fm][fn] = __builtin_amdgcn_mfma_f32_16x16x32_f16(a[fm][0], b0r[fn][0], acc[fm][fn], 0, 0, 0);
                acc[fm][fn] = __builtin_amdgcn_mfma_f32_16x16x32_f16(a[fm][1], b0r[fn][1], acc[fm][fn], 0, 0, 0);
            }
        __builtin_amdgcn_s_setprio(0);
        __builtin_amdgcn_s_barrier();

        // ---------------- P1 ----------------
        #pragma unroll
        for (int fn = 0; fn < 2; ++fn) {
            b1r[fn][0] = *(const f16x8*)(Bc + (rB + (fn + 2) * 16) * 64 + swk0);
            b1r[fn][1] = *(const f16x8*)(Bc + (rB + (fn + 2) * 16) * 64 + swk1);
        }
        __builtin_amdgcn_s_barrier();
        asm volatile("s_waitcnt lgkmcnt(0)" ::: "memory");
        __builtin_amdgcn_sched_barrier(0);
        __builtin_amdgcn_s_setprio(1);
        #pragma unroll
        for (int fm = 0; fm < 4; ++fm)
            #pragma unroll
            for (int fn = 0; fn < 2; ++fn) {
                acc[fm][fn + 2] = __builtin_amdgcn_mfma_f32_16x16x32_f16(a[fm][0], b1r[fn][0], acc[fm][fn + 2], 0, 0, 0);
                acc[fm][fn + 2] = __builtin_amdgcn_mfma_f32_16x16x32_f16(a[fm][1], b1r[fn][1], acc[fm][fn + 2], 0, 0, 0);
            }
        __builtin_amdgcn_s_setprio(0);
        __builtin_amdgcn_s_barrier();

        // ---------------- P2 ----------------
        #pragma unroll
        for (int fm = 0; fm < 4; ++fm) {
            a[fm][0] = *(const f16x8*)(Ac + (rA + (fm + 4) * 16) * 64 + swk0);
            a[fm][1] = *(const f16x8*)(Ac + (rA + (fm + 4) * 16) * 64 + swk1);
        }
        stgB(Bc, 0, kt2);
        __builtin_amdgcn_s_barrier();
        asm volatile("s_waitcnt lgkmcnt(0)" ::: "memory");
        __builtin_amdgcn_sched_barrier(0);
        __builtin_amdgcn_s_setprio(1);
        #pragma unroll
        for (int fm = 0; fm < 4; ++fm)
            #pragma unroll
            for (int fn = 0; fn < 2; ++fn) {
                acc[fm + 4][fn + 2] = __builtin_amdgcn_mfma_f32_16x16x32_f16(a[fm][0], b1r[fn][0], acc[fm + 4][fn + 2], 0, 0, 0);
                acc[fm + 4][fn + 2] = __builtin_amdgcn_mfma_f32_16x16x32_f16(a[fm][1], b1r[fn][1], acc[fm + 4][fn + 2], 0, 0, 0);
            }
        __builtin_amdgcn_s_setprio(0);
        __builtin_amdgcn_s_barrier();

        // ---------------- P3 ----------------
        stgB(Bc, 1, kt2);
        stgA(Ac, 0, kt2);
        __builtin_amdgcn_s_barrier();
        __builtin_amdgcn_s_setprio(1);
        #pragma unroll
        for (int fm = 0; fm < 4; ++fm)
            #pragma unroll
            for (int fn = 0; fn < 2; ++fn) {
                acc[fm + 4][fn] = __builtin_amdgcn_mfma_f32_16x16x32_f16(a[fm][0], b0r[fn][0], acc[fm + 4][fn], 0, 0, 0);
                acc[fm + 4][fn] = __builtin_amdgcn_mfma_f32_16x16x32_f16(a[fm][1], b0r[fn][1], acc[fm + 4][fn], 0, 0, 0);
            }
        __builtin_amdgcn_s_setprio(0);
        asm volatile("s_waitcnt vmcnt(6)" ::: "memory");
        __builtin_amdgcn_s_barrier();

        f16* tp;
        tp = Ac; Ac = Ao; Ao = tp;
        tp = Bc; Bc = Bo; Bo = tp;
    }
    asm volatile("s_waitcnt vmcnt(0)" ::: "memory");

    // epilogue: col = n-side via rl, row = m-side via g*4+r (same mapping as 128^2 kernel)
    #pragma unroll
    for (int fm = 0; fm < 8; ++fm) {
        #pragma unroll
        for (int fn = 0; fn < 4; ++fn) {
            const int col = n0 + wc * 64 + fn * 16 + rl;
            const float bv = bias[col];
            #pragma unroll
            for (int r = 0; r < 4; ++r) {
                const int row = m0 + wr * 128 + fm * 16 + g * 4 + r;
                const float v = acc[fm][fn][r] + bv;
                outH[(size_t)row * N + col] = (f16)gelu_exact(v);
            }
        }
    }
}

// ---------------- GEMM (NT) 128^2 ring-3 (swizzled LDS) --------------------
// EPI: 1 = +bias, fp16 out TRANSPOSED per batch: out[z][col][row%2048] (T=2048)
//      2 = fp16 out [M][N] (batched)
//      3 = fp32 out + xadd (batched)
template <int EPI>
__global__ __launch_bounds__(256, 3)
void gemm_nt_kernel(const f16* __restrict__ A, const f16* __restrict__ Bt,
                    const float* __restrict__ bias,
                    const float* __restrict__ xadd,
                    f16* __restrict__ outH, float* __restrict__ outF,
                    int M, int N, int K,
                    long long batchA, long long batchB, long long batchC) {
    __shared__ __attribute__((aligned(16))) f16 sA[3][128 * 32];
    __shared__ __attribute__((aligned(16))) f16 sB[3][128 * 32];

    const int z = blockIdx.z;
    A  += (size_t)z * batchA;
    Bt += (size_t)z * batchB;

    const int m0 = blockIdx.x * 128;
    const int n0 = blockIdx.y * 128;
    const int t = threadIdx.x;
    const int l = t & 63;
    const int wid = t >> 6;
    const int wm = (wid >> 1) * 64;
    const int wn = (wid & 1) * 64;

    f32x4 acc[4][4] = {};

    const int rl = l & 15;
    const int nk = K >> 5;

    // staging with swizzled source: chunk c -> row c>>2, slot c&3;
    // source k-slot = slot ^ (row&3) (same for c and c+256: row differs by 64)
    const int row0 = t >> 2;
    const int kb = ((t & 3) ^ (row0 & 3)) * 8;
    const f16* Ag0 = A  + (size_t)(m0 + row0) * K + kb;
    const f16* Ag1 = A  + (size_t)(m0 + row0 + 64) * K + kb;
    const f16* Bg0 = Bt + (size_t)(n0 + row0) * K + kb;
    const f16* Bg1 = Bt + (size_t)(n0 + row0 + 64) * K + kb;
    const int lo0 = wid * 512;
    const int lo1 = 2048 + wid * 512;

    // read: k-slot g at row r lives in LDS slot g^(r&3); r&3 == rl&3
    const int swk = (((l >> 4) ^ (rl & 3))) * 8;

    // prologue: stage tiles 0 and 1 into ring slots 0,1
    gload_lds16(Ag0,      sA[0] + lo0);
    gload_lds16(Ag1,      sA[0] + lo1);
    gload_lds16(Bg0,      sB[0] + lo0);
    gload_lds16(Bg1,      sB[0] + lo1);
    gload_lds16(Ag0 + 32, sA[1] + lo0);
    gload_lds16(Ag1 + 32, sA[1] + lo1);
    gload_lds16(Bg0 + 32, sB[1] + lo0);
    gload_lds16(Bg1 + 32, sB[1] + lo1);

    f16 *curA = sA[0], *nxtA = sA[1], *farA = sA[2];
    f16 *curB = sB[0], *nxtB = sB[1], *farB = sB[2];

    for (int kt = 0; kt < nk; ++kt) {
        asm volatile("s_waitcnt vmcnt(4)" ::: "memory");
        __builtin_amdgcn_s_barrier();

        const int ktn = (kt + 2 < nk) ? kt + 2 : nk - 1;
        const int kof = ktn * 32;
        gload_lds16(Ag0 + kof, farA + lo0);
        gload_lds16(Ag1 + kof, farA + lo1);
        gload_lds16(Bg0 + kof, farB + lo0);
        gload_lds16(Bg1 + kof, farB + lo1);

        f16x8 a[4], b[4];
        #pragma unroll
        for (int f = 0; f < 4; ++f) {
            a[f] = *(const f16x8*)&curA[(wm + f * 16 + rl) * 32 + swk];
            b[f] = *(const f16x8*)&curB[(wn + f * 16 + rl) * 32 + swk];
        }
        #pragma unroll
        for (int fm = 0; fm < 4; ++fm)
            #pragma unroll
            for (int fn = 0; fn < 4; ++fn)
                acc[fm][fn] = __builtin_amdgcn_mfma_f32_16x16x32_f16(
                    a[fm], b[fn], acc[fm][fn], 0, 0, 0);

        f16* tA = curA; curA = nxtA; nxtA = farA; farA = tA;
        f16* tB = curB; curB = nxtB; nxtB = farB; farB = tB;
    }
    asm volatile("s_waitcnt vmcnt(0)" ::: "memory");

    // epilogue: D mapping col = l&15, row = (l>>4)*4 + r
    const int rh = l >> 4;
    const float* xaddz = xadd;
    f16* outHz = outH;
    float* outFz = outF;
    if (EPI == 3) {
        outFz += (size_t)z * batchC;
        xaddz += (size_t)z * batchC;
    } else if (EPI == 2) {
        outHz += (size_t)z * batchC;
    }
    #pragma unroll
    for (int fm = 0; fm < 4; ++fm) {
        #pragma unroll
        for (int fn = 0; fn < 4; ++fn) {
            const int col = n0 + wn + fn * 16 + rl;
            if (EPI == 1) {
                const int row0o = m0 + wm + fm * 16 + rh * 4;
                const int zz = row0o >> 11;
                const int rr = row0o & 2047;
                const float bv = bias[col];
                f16x4 o;
                #pragma unroll
                for (int r = 0; r < 4; ++r) o[r] = (f16)(acc[fm][fn][r] + bv);
                *(f16x4*)(outH + ((size_t)zz * N + col) * 2048 + rr) = o;
            } else {
                #pragma unroll
                for (int r = 0; r < 4; ++r) {
                    const int row = m0 + wm + fm * 16 + rh * 4 + r;
                    float v = acc[fm][fn][r];
                    const size_t idx = (size_t)row * N + col;
                    if (EPI == 2) {
                        outHz[idx] = (f16)v;
                    } else {
                        outFz[idx] = v + xaddz[idx];
                    }
                }
            }
        }
    }
}

extern "C" void kernel_launch(void* const* d_in, const int* in_sizes, int n_in,
                              void* d_out, int out_size, void* d_ws, size_t ws_size,
                              hipStream_t stream) {
    const float* x     = (const float*)d_in[0];
    const float* gamma = (const float*)d_in[1];
    const float* beta  = (const float*)d_in[2];
    const float* w1    = (const float*)d_in[3];
    const float* b1    = (const float*)d_in[4];
    const float* w2    = (const float*)d_in[5];
    const float* b2    = (const float*)d_in[6];
    float* out = (float*)d_out;

    const int BS = 4, T = 2048, DIM = 1024, HID = 2048;
    const int M = BS * T;  // 8192
    const long long MB = 1024 * 1024;

    // workspace layout (112 MiB total)
    char* ws = (char*)d_ws;
    f16*   x_h  = (f16*)(ws + 0 * MB);    // 16 MiB [M][DIM]
    f16*   y_h  = (f16*)(ws + 16 * MB);   // 16 MiB [M][DIM]
    f16*   h    = (f16*)(ws + 32 * MB);   // 32 MiB [M][HID]
    float* pre  = (float*)h;              // alias: h dead after GEMM2
    f16*   y2t  = (f16*)(ws + 64 * MB);   // 16 MiB [BS][DIM][T]
    f16*   x_t  = (f16*)(ws + 80 * MB);   // 16 MiB [BS][DIM][T]
    f16*   G    = (f16*)(ws + 96 * MB);   // 8 MiB  [BS][DIM][DIM]
    f16*   w1t  = (f16*)(ws + 104 * MB);  // 4 MiB  [HID][DIM]
    f16*   w2t  = (f16*)(ws + 108 * MB);  // 4 MiB  [DIM][HID]

    // 1) first LN + fp16 casts
    ln_cast_kernel<<<M, 256, 0, stream>>>(x, gamma, beta, y_h, x_h);

    // 2) weight transposes to fp16 [N][K]
    transpose_cast_kernel<<<dim3(HID / 32, DIM / 32), 256, 0, stream>>>(w1, w1t, DIM, HID);
    transpose_cast_kernel<<<dim3(DIM / 32, HID / 32), 256, 0, stream>>>(w2, w2t, HID, DIM);

    // 3) h = gelu(y @ w1 + b1)   [M][HID]  -- 256^2 8-phase kernel
    gemm256_nt_kernel<0><<<dim3(M / 256, HID / 256), 512, 0, stream>>>(
        y_h, w1t, b1, h, M, HID, DIM);

    // 4) y2t[z][f][t] = (h @ w2 + b2)[z*T+t][f]   (transposed epilogue)
    gemm_nt_kernel<1><<<dim3(M / 128, DIM / 128, 1), 256, 0, stream>>>(
        h, w2t, b2, nullptr, y2t, nullptr, M, DIM, HID, 0, 0, 0);

    // 5) x_t[z][f][t] = x_h[z*T+t][f]
    transpose_f16_kernel<<<dim3(DIM / 32, T / 32, BS), 256, 0, stream>>>(x_h, x_t, T, DIM);

    // 6) G'[z][f2][f1] = sum_t y2t[z][f2][t] * x_t[z][f1][t]
    gemm_nt_kernel<2><<<dim3(DIM / 128, DIM / 128, BS), 256, 0, stream>>>(
        y2t, x_t, nullptr, nullptr, G, nullptr, DIM, DIM, T,
        (long long)DIM * T, (long long)DIM * T, (long long)DIM * DIM);

    // 7) pre[z][t][f] = sum_k x_h[z][t][k] * G'[z][f][k] + x
    gemm_nt_kernel<3><<<dim3(T / 128, DIM / 128, BS), 256, 0, stream>>>(
        x_h, G, nullptr, x, nullptr, pre, T, DIM, DIM,
        (long long)T * DIM, (long long)DIM * DIM, (long long)T * DIM);

    // 8) final LN
    ln_final_kernel<<<M, 256, 0, stream>>>(pre, gamma, beta, out);
}

// Round 6
// 198.444 us; speedup vs baseline: 1.5309x; 1.0694x over previous
//
#include <hip/hip_runtime.h>
#include <hip/hip_fp16.h>

typedef _Float16 f16;
typedef _Float16 f16x8 __attribute__((ext_vector_type(8)));
typedef _Float16 f16x4 __attribute__((ext_vector_type(4)));
typedef float f32x4 __attribute__((ext_vector_type(4)));

#define LN_EPS 1e-5f

// erf via Abramowitz-Stegun 7.1.26 (|eps| <= 1.5e-7)
__device__ __forceinline__ float erf_fast(float x) {
    const float ax = __builtin_fabsf(x);
    const float t = 1.0f / (1.0f + 0.3275911f * ax);
    const float y = t * (0.254829592f +
                    t * (-0.284496736f +
                    t * (1.421413741f +
                    t * (-1.453152027f +
                    t * 1.061405429f))));
    const float r = 1.0f - y * __expf(-ax * ax);
    return __builtin_copysignf(r, x);
}

__device__ __forceinline__ float gelu_exact(float v) {
    return 0.5f * v * (1.0f + erf_fast(v * 0.70710678118654752440f));
}

// async global -> LDS, 16B per lane; lds dest is wave-uniform base (+lane*16 by HW)
__device__ __forceinline__ void gload_lds16(const f16* g, f16* l) {
    __builtin_amdgcn_global_load_lds(
        (const __attribute__((address_space(1))) unsigned int*)(g),
        (__attribute__((address_space(3))) unsigned int*)(l),
        16, 0, 0);
}

// ---------------- LayerNorm(x) -> y_h (fp16), plus x -> x_h (fp16) ----------
__global__ __launch_bounds__(256)
void ln_cast_kernel(const float* __restrict__ x,
                    const float* __restrict__ gamma,
                    const float* __restrict__ beta,
                    f16* __restrict__ y_h,
                    f16* __restrict__ x_h) {
    const int row = blockIdx.x;
    const int t = threadIdx.x;
    const size_t base = (size_t)row * 1024;
    float4 v = ((const float4*)(x + base))[t];
    float s  = v.x + v.y + v.z + v.w;
    float s2 = v.x*v.x + v.y*v.y + v.z*v.z + v.w*v.w;
    #pragma unroll
    for (int off = 32; off > 0; off >>= 1) {
        s  += __shfl_down(s, off, 64);
        s2 += __shfl_down(s2, off, 64);
    }
    __shared__ float ls[4], ls2[4];
    const int wid = t >> 6;
    if ((t & 63) == 0) { ls[wid] = s; ls2[wid] = s2; }
    __syncthreads();
    if (t == 0) {
        ls[0]  = ls[0] + ls[1] + ls[2] + ls[3];
        ls2[0] = ls2[0] + ls2[1] + ls2[2] + ls2[3];
    }
    __syncthreads();
    const float mu   = ls[0] * (1.0f / 1024.0f);
    const float var  = ls2[0] * (1.0f / 1024.0f) - mu * mu;
    const float rstd = rsqrtf(var + LN_EPS);
    const float4 g  = ((const float4*)gamma)[t];
    const float4 bt = ((const float4*)beta)[t];
    f16x4 yo, xo;
    yo[0] = (f16)((v.x - mu) * rstd * g.x + bt.x);
    yo[1] = (f16)((v.y - mu) * rstd * g.y + bt.y);
    yo[2] = (f16)((v.z - mu) * rstd * g.z + bt.z);
    yo[3] = (f16)((v.w - mu) * rstd * g.w + bt.w);
    xo[0] = (f16)v.x; xo[1] = (f16)v.y; xo[2] = (f16)v.z; xo[3] = (f16)v.w;
    *(f16x4*)(y_h + base + t * 4) = yo;
    *(f16x4*)(x_h + base + t * 4) = xo;
}

// ---------------- final LayerNorm: pre (fp32) -> out (fp32) ----------------
__global__ __launch_bounds__(256)
void ln_final_kernel(const float* __restrict__ pre,
                     const float* __restrict__ gamma,
                     const float* __restrict__ beta,
                     float* __restrict__ out) {
    const int row = blockIdx.x;
    const int t = threadIdx.x;
    const size_t base = (size_t)row * 1024;
    float4 v = ((const float4*)(pre + base))[t];
    float s  = v.x + v.y + v.z + v.w;
    float s2 = v.x*v.x + v.y*v.y + v.z*v.z + v.w*v.w;
    #pragma unroll
    for (int off = 32; off > 0; off >>= 1) {
        s  += __shfl_down(s, off, 64);
        s2 += __shfl_down(s2, off, 64);
    }
    __shared__ float ls[4], ls2[4];
    const int wid = t >> 6;
    if ((t & 63) == 0) { ls[wid] = s; ls2[wid] = s2; }
    __syncthreads();
    if (t == 0) {
        ls[0]  = ls[0] + ls[1] + ls[2] + ls[3];
        ls2[0] = ls2[0] + ls2[1] + ls2[2] + ls2[3];
    }
    __syncthreads();
    const float mu   = ls[0] * (1.0f / 1024.0f);
    const float var  = ls2[0] * (1.0f / 1024.0f) - mu * mu;
    const float rstd = rsqrtf(var + LN_EPS);
    const float4 g  = ((const float4*)gamma)[t];
    const float4 bt = ((const float4*)beta)[t];
    float4 o;
    o.x = (v.x - mu) * rstd * g.x + bt.x;
    o.y = (v.y - mu) * rstd * g.y + bt.y;
    o.z = (v.z - mu) * rstd * g.z + bt.z;
    o.w = (v.w - mu) * rstd * g.w + bt.w;
    ((float4*)(out + base))[t] = o;
}

// ------------- transpose + cast fp32 [R,C] -> fp16 [C,R] -------------------
__global__ __launch_bounds__(256)
void transpose_cast_kernel(const float* __restrict__ src,
                           f16* __restrict__ dst, int R, int C) {
    __shared__ float tile[32][33];
    const int c0 = blockIdx.x * 32, r0 = blockIdx.y * 32;
    const int tx = threadIdx.x & 31, ty = threadIdx.x >> 5;
    #pragma unroll
    for (int i = 0; i < 4; ++i) {
        const int r = ty + i * 8;
        tile[r][tx] = src[(size_t)(r0 + r) * C + c0 + tx];
    }
    __syncthreads();
    #pragma unroll
    for (int i = 0; i < 4; ++i) {
        const int r = ty + i * 8;
        dst[(size_t)(c0 + r) * R + r0 + tx] = (f16)tile[tx][r];
    }
}

// ------------- batched transpose fp16 [R,C] -> fp16 [C,R] ------------------
__global__ __launch_bounds__(256)
void transpose_f16_kernel(const f16* __restrict__ src,
                          f16* __restrict__ dst, int R, int C) {
    __shared__ f16 tile[32][33];
    const size_t zb = (size_t)blockIdx.z * R * C;
    src += zb; dst += zb;
    const int c0 = blockIdx.x * 32, r0 = blockIdx.y * 32;
    const int tx = threadIdx.x & 31, ty = threadIdx.x >> 5;
    #pragma unroll
    for (int i = 0; i < 4; ++i) {
        const int r = ty + i * 8;
        tile[r][tx] = src[(size_t)(r0 + r) * C + c0 + tx];
    }
    __syncthreads();
    #pragma unroll
    for (int i = 0; i < 4; ++i) {
        const int r = ty + i * 8;
        dst[(size_t)(c0 + r) * R + r0 + tx] = tile[tx][r];
    }
}

// ============ 256x256 8-wave GEMM (NT), BK=64, 8-phase (g0: gelu+bias) =====
template <int EPI>
__global__ __launch_bounds__(512, 2)
void gemm256_nt_kernel(const f16* __restrict__ A, const f16* __restrict__ Bt,
                       const float* __restrict__ bias, f16* __restrict__ outH,
                       int M, int N, int K) {
    __shared__ __attribute__((aligned(16))) f16 sAbuf[2][256 * 64];
    __shared__ __attribute__((aligned(16))) f16 sBbuf[2][256 * 64];

    const int m0 = blockIdx.x * 256;
    const int n0 = blockIdx.y * 256;
    const int t = threadIdx.x;
    const int l = t & 63;
    const int wid = t >> 6;
    const int wr = wid >> 2;      // 0-1
    const int wc = wid & 3;       // 0-3
    const int rl = l & 15;
    const int g  = l >> 4;        // 0-3
    const int nk = K >> 6;

    const int rowS = wid * 16 + (l >> 3);
    const int kbS  = ((l & 7) ^ ((l >> 3) & 7)) * 8;
    const f16* pA = A  + (size_t)(m0 + rowS) * K + kbS;
    const f16* pB = Bt + (size_t)(n0 + rowS) * K + kbS;
    const int ldsS = wid * 1024;

    const int rA = wr * 128 + rl;
    const int rB = wc * 64 + rl;
    const int swk0 = ((g)     ^ (rl & 7)) * 8;
    const int swk1 = ((4 + g) ^ (rl & 7)) * 8;

    f32x4 acc[8][4] = {};

    const long long hstep = (long long)128 * K;

    auto stgA = [&](f16* dst, int h, int kc) {
        const f16* s = pA + (size_t)h * hstep + kc * 64;
        f16* d = dst + h * 8192 + ldsS;
        gload_lds16(s, d);
        gload_lds16(s + 8 * K, d + 512);
    };
    auto stgB = [&](f16* dst, int h, int kc) {
        const f16* s = pB + (size_t)h * hstep + kc * 64;
        f16* d = dst + h * 8192 + ldsS;
        gload_lds16(s, d);
        gload_lds16(s + 8 * K, d + 512);
    };

    f16* bufA0 = sAbuf[0]; f16* bufA1 = sAbuf[1];
    f16* bufB0 = sBbuf[0]; f16* bufB1 = sBbuf[1];

    const int t1 = (nk > 1) ? 1 : 0;
    stgA(bufA0, 0, 0); stgA(bufA0, 1, 0);
    stgB(bufB0, 0, 0); stgB(bufB0, 1, 0);
    stgB(bufB1, 0, t1); stgB(bufB1, 1, t1);
    stgA(bufA1, 0, t1);
    asm volatile("s_waitcnt vmcnt(6)" ::: "memory");
    __builtin_amdgcn_s_barrier();

    f16 *Ac = bufA0, *Ao = bufA1, *Bc = bufB0, *Bo = bufB1;

    f16x8 a[4][2], b0r[2][2], b1r[2][2];

    for (int kt = 0; kt < nk; ++kt) {
        const int kt1 = (kt + 1 < nk) ? kt + 1 : nk - 1;
        const int kt2 = (kt + 2 < nk) ? kt + 2 : nk - 1;

        // P0
        #pragma unroll
        for (int fm = 0; fm < 4; ++fm) {
            a[fm][0] = *(const f16x8*)(Ac + (rA + fm * 16) * 64 + swk0);
            a[fm][1] = *(const f16x8*)(Ac + (rA + fm * 16) * 64 + swk1);
        }
        #pragma unroll
        for (int fn = 0; fn < 2; ++fn) {
            b0r[fn][0] = *(const f16x8*)(Bc + (rB + fn * 16) * 64 + swk0);
            b0r[fn][1] = *(const f16x8*)(Bc + (rB + fn * 16) * 64 + swk1);
        }
        stgA(Ao, 1, kt1);
        __builtin_amdgcn_s_barrier();
        asm volatile("s_waitcnt lgkmcnt(0)" ::: "memory");
        __builtin_amdgcn_sched_barrier(0);
        __builtin_amdgcn_s_setprio(1);
        #pragma unroll
        for (int fm = 0; fm < 4; ++fm)
            #pragma unroll
            for (int fn = 0; fn < 2; ++fn) {
                acc[fm][fn] = __builtin_amdgcn_mfma_f32_16x16x32_f16(a[fm][0], b0r[fn][0], acc[fm][fn], 0, 0, 0);
                acc[fm][fn] = __builtin_amdgcn_mfma_f32_16x16x32_f16(a[fm][1], b0r[fn][1], acc[fm][fn], 0, 0, 0);
            }
        __builtin_amdgcn_s_setprio(0);
        __builtin_amdgcn_s_barrier();

        // P1
        #pragma unroll
        for (int fn = 0; fn < 2; ++fn) {
            b1r[fn][0] = *(const f16x8*)(Bc + (rB + (fn + 2) * 16) * 64 + swk0);
            b1r[fn][1] = *(const f16x8*)(Bc + (rB + (fn + 2) * 16) * 64 + swk1);
        }
        __builtin_amdgcn_s_barrier();
        asm volatile("s_waitcnt lgkmcnt(0)" ::: "memory");
        __builtin_amdgcn_sched_barrier(0);
        __builtin_amdgcn_s_setprio(1);
        #pragma unroll
        for (int fm = 0; fm < 4; ++fm)
            #pragma unroll
            for (int fn = 0; fn < 2; ++fn) {
                acc[fm][fn + 2] = __builtin_amdgcn_mfma_f32_16x16x32_f16(a[fm][0], b1r[fn][0], acc[fm][fn + 2], 0, 0, 0);
                acc[fm][fn + 2] = __builtin_amdgcn_mfma_f32_16x16x32_f16(a[fm][1], b1r[fn][1], acc[fm][fn + 2], 0, 0, 0);
            }
        __builtin_amdgcn_s_setprio(0);
        __builtin_amdgcn_s_barrier();

        // P2
        #pragma unroll
        for (int fm = 0; fm < 4; ++fm) {
            a[fm][0] = *(const f16x8*)(Ac + (rA + (fm + 4) * 16) * 64 + swk0);
            a[fm][1] = *(const f16x8*)(Ac + (rA + (fm + 4) * 16) * 64 + swk1);
        }
        stgB(Bc, 0, kt2);
        __builtin_amdgcn_s_barrier();
        asm volatile("s_waitcnt lgkmcnt(0)" ::: "memory");
        __builtin_amdgcn_sched_barrier(0);
        __builtin_amdgcn_s_setprio(1);
        #pragma unroll
        for (int fm = 0; fm < 4; ++fm)
            #pragma unroll
            for (int fn = 0; fn < 2; ++fn) {
                acc[fm + 4][fn + 2] = __builtin_amdgcn_mfma_f32_16x16x32_f16(a[fm][0], b1r[fn][0], acc[fm + 4][fn + 2], 0, 0, 0);
                acc[fm + 4][fn + 2] = __builtin_amdgcn_mfma_f32_16x16x32_f16(a[fm][1], b1r[fn][1], acc[fm + 4][fn + 2], 0, 0, 0);
            }
        __builtin_amdgcn_s_setprio(0);
        __builtin_amdgcn_s_barrier();

        // P3
        stgB(Bc, 1, kt2);
        stgA(Ac, 0, kt2);
        __builtin_amdgcn_s_barrier();
        __builtin_amdgcn_s_setprio(1);
        #pragma unroll
        for (int fm = 0; fm < 4; ++fm)
            #pragma unroll
            for (int fn = 0; fn < 2; ++fn) {
                acc[fm + 4][fn] = __builtin_amdgcn_mfma_f32_16x16x32_f16(a[fm][0], b0r[fn][0], acc[fm + 4][fn], 0, 0, 0);
                acc[fm + 4][fn] = __builtin_amdgcn_mfma_f32_16x16x32_f16(a[fm][1], b0r[fn][1], acc[fm + 4][fn], 0, 0, 0);
            }
        __builtin_amdgcn_s_setprio(0);
        asm volatile("s_waitcnt vmcnt(6)" ::: "memory");
        __builtin_amdgcn_s_barrier();

        f16* tp;
        tp = Ac; Ac = Ao; Ao = tp;
        tp = Bc; Bc = Bo; Bo = tp;
    }
    asm volatile("s_waitcnt vmcnt(0)" ::: "memory");

    #pragma unroll
    for (int fm = 0; fm < 8; ++fm) {
        #pragma unroll
        for (int fn = 0; fn < 4; ++fn) {
            const int col = n0 + wc * 64 + fn * 16 + rl;
            const float bv = bias[col];
            #pragma unroll
            for (int r = 0; r < 4; ++r) {
                const int row = m0 + wr * 128 + fm * 16 + g * 4 + r;
                const float v = acc[fm][fn][r] + bv;
                outH[(size_t)row * N + col] = (f16)gelu_exact(v);
            }
        }
    }
}

// ====== 256x128 8-wave GEMM (NT), BK=64, ring-3 LDS, 4 phases/K-tile =======
// Wave grid 4(M) x 2(N), wave tile 64x64. LDS: A 3x32KB + B 3x16KB = 144KB.
// Staging: 6 units/K-tile (A:4, B:2), each = 512 lanes x 16B. Loop top:
// vmcnt(6) [tile kt landed; kt+1's 6 in flight] -> barrier -> phases issue
// tile kt+2 into slot(kt+2)%3 (= slot whose reads finished in iter kt-1).
// Swizzle: 16B slot s of row r holds k-slot s^(r&7); pre-swizzled global src.
// EPI: 1 = +bias, fp16 out TRANSPOSED per batch out[z][col][row%2048] (T=2048)
//      3 = fp32 out + xadd (batched via blockIdx.z)
template <int EPI>
__global__ __launch_bounds__(512, 2)
void gemm256x128_nt_kernel(const f16* __restrict__ A, const f16* __restrict__ Bt,
                           const float* __restrict__ bias,
                           const float* __restrict__ xadd,
                           f16* __restrict__ outH, float* __restrict__ outF,
                           int M, int N, int K,
                           long long batchA, long long batchB, long long batchC) {
    __shared__ __attribute__((aligned(16))) f16 sA[3][256 * 64];
    __shared__ __attribute__((aligned(16))) f16 sB[3][128 * 64];

    const int z = blockIdx.z;
    A  += (size_t)z * batchA;
    Bt += (size_t)z * batchB;

    const int m0 = blockIdx.x * 256;
    const int n0 = blockIdx.y * 128;
    const int t = threadIdx.x;
    const int l = t & 63;
    const int wid = t >> 6;
    const int wr = wid >> 1;      // 0-3 (M)
    const int wc = wid & 1;       // 0-1 (N)
    const int rl = l & 15;
    const int g  = l >> 4;        // 0-3
    const int nk = K >> 6;

    // staging: unit = 512 lanes x 16B = 64 rows x 64 f16. thread t covers
    // row (t>>3) within unit, slot t&7; source k-slot = slot ^ (row&7).
    const int rowS = t >> 3;                       // 0..63
    const int kbS  = ((t & 7) ^ (rowS & 7)) * 8;
    const f16* pA = A  + (size_t)(m0 + rowS) * K + kbS;
    const f16* pB = Bt + (size_t)(n0 + rowS) * K + kbS;
    const int ldsS = wid * 512;   // wave-uniform base within unit (HW +lane*16B)

    const int rA = wr * 64 + rl;
    const int rB = wc * 64 + rl;
    const int swk0 = ((g)     ^ (rl & 7)) * 8;
    const int swk1 = ((4 + g) ^ (rl & 7)) * 8;

    f32x4 acc[4][4] = {};

    auto stgA = [&](f16* dst, int u, int kc) {   // u = 0..3
        gload_lds16(pA + (size_t)u * 64 * K + kc * 64, dst + u * 4096 + ldsS);
    };
    auto stgB = [&](f16* dst, int u, int kc) {   // u = 0..1
        gload_lds16(pB + (size_t)u * 64 * K + kc * 64, dst + u * 4096 + ldsS);
    };

    // prologue: tiles 0 and 1 (12 units outstanding)
    const int t1 = (nk > 1) ? 1 : 0;
    #pragma unroll
    for (int u = 0; u < 4; ++u) stgA(sA[0], u, 0);
    #pragma unroll
    for (int u = 0; u < 2; ++u) stgB(sB[0], u, 0);
    #pragma unroll
    for (int u = 0; u < 4; ++u) stgA(sA[1], u, t1);
    #pragma unroll
    for (int u = 0; u < 2; ++u) stgB(sB[1], u, t1);

    f16 *curA = sA[0], *nxtA = sA[1], *farA = sA[2];
    f16 *curB = sB[0], *nxtB = sB[1], *farB = sB[2];

    f16x8 a[4][2], b[4][2];

    for (int kt = 0; kt < nk; ++kt) {
        // tile kt landed for this wave; kt+1's 6 units stay in flight
        asm volatile("s_waitcnt vmcnt(6)" ::: "memory");
        __builtin_amdgcn_s_barrier();

        const int kt2 = (kt + 2 < nk) ? kt + 2 : nk - 1;

        // P0: rd a01+b01, stg A-units 0,1 of kt+2; MFMA fm01 x fn01
        #pragma unroll
        for (int fm = 0; fm < 2; ++fm) {
            a[fm][0] = *(const f16x8*)(curA + (rA + fm * 16) * 64 + swk0);
            a[fm][1] = *(const f16x8*)(curA + (rA + fm * 16) * 64 + swk1);
        }
        #pragma unroll
        for (int fn = 0; fn < 2; ++fn) {
            b[fn][0] = *(const f16x8*)(curB + (rB + fn * 16) * 64 + swk0);
            b[fn][1] = *(const f16x8*)(curB + (rB + fn * 16) * 64 + swk1);
        }
        stgA(farA, 0, kt2);
        stgA(farA, 1, kt2);
        asm volatile("s_waitcnt lgkmcnt(0)" ::: "memory");
        __builtin_amdgcn_sched_barrier(0);
        __builtin_amdgcn_s_setprio(1);
        #pragma unroll
        for (int fm = 0; fm < 2; ++fm)
            #pragma unroll
            for (int fn = 0; fn < 2; ++fn) {
                acc[fm][fn] = __builtin_amdgcn_mfma_f32_16x16x32_f16(a[fm][0], b[fn][0], acc[fm][fn], 0, 0, 0);
                acc[fm][fn] = __builtin_amdgcn_mfma_f32_16x16x32_f16(a[fm][1], b[fn][1], acc[fm][fn], 0, 0, 0);
            }
        __builtin_amdgcn_s_setprio(0);

        // P1: rd b23, stg A-units 2,3; MFMA fm01 x fn23
        #pragma unroll
        for (int fn = 2; fn < 4; ++fn) {
            b[fn][0] = *(const f16x8*)(curB + (rB + fn * 16) * 64 + swk0);
            b[fn][1] = *(const f16x8*)(curB + (rB + fn * 16) * 64 + swk1);
        }
        stgA(farA, 2, kt2);
        stgA(farA, 3, kt2);
        asm volatile("s_waitcnt lgkmcnt(0)" ::: "memory");
        __builtin_amdgcn_sched_barrier(0);
        __builtin_amdgcn_s_setprio(1);
        #pragma unroll
        for (int fm = 0; fm < 2; ++fm)
            #pragma unroll
            for (int fn = 2; fn < 4; ++fn) {
                acc[fm][fn] = __builtin_amdgcn_mfma_f32_16x16x32_f16(a[fm][0], b[fn][0], acc[fm][fn], 0, 0, 0);
                acc[fm][fn] = __builtin_amdgcn_mfma_f32_16x16x32_f16(a[fm][1], b[fn][1], acc[fm][fn], 0, 0, 0);
            }
        __builtin_amdgcn_s_setprio(0);

        // P2: rd a23, stg B-units 0,1; MFMA fm23 x fn23
        #pragma unroll
        for (int fm = 2; fm < 4; ++fm) {
            a[fm][0] = *(const f16x8*)(curA + (rA + fm * 16) * 64 + swk0);
            a[fm][1] = *(const f16x8*)(curA + (rA + fm * 16) * 64 + swk1);
        }
        stgB(farB, 0, kt2);
        stgB(farB, 1, kt2);
        asm volatile("s_waitcnt lgkmcnt(0)" ::: "memory");
        __builtin_amdgcn_sched_barrier(0);
        __builtin_amdgcn_s_setprio(1);
        #pragma unroll
        for (int fm = 2; fm < 4; ++fm)
            #pragma unroll
            for (int fn = 2; fn < 4; ++fn) {
                acc[fm][fn] = __builtin_amdgcn_mfma_f32_16x16x32_f16(a[fm][0], b[fn][0], acc[fm][fn], 0, 0, 0);
                acc[fm][fn] = __builtin_amdgcn_mfma_f32_16x16x32_f16(a[fm][1], b[fn][1], acc[fm][fn], 0, 0, 0);
            }
        __builtin_amdgcn_s_setprio(0);

        // P3: MFMA fm23 x fn01 (all operands in regs)
        __builtin_amdgcn_s_setprio(1);
        #pragma unroll
        for (int fm = 2; fm < 4; ++fm)
            #pragma unroll
            for (int fn = 0; fn < 2; ++fn) {
                acc[fm][fn] = __builtin_amdgcn_mfma_f32_16x16x32_f16(a[fm][0], b[fn][0], acc[fm][fn], 0, 0, 0);
                acc[fm][fn] = __builtin_amdgcn_mfma_f32_16x16x32_f16(a[fm][1], b[fn][1], acc[fm][fn], 0, 0, 0);
            }
        __builtin_amdgcn_s_setprio(0);

        // rotate ring
        f16* tp;
        tp = curA; curA = nxtA; nxtA = farA; farA = tp;
        tp = curB; curB = nxtB; nxtB = farB; farB = tp;
    }
    asm volatile("s_waitcnt vmcnt(0)" ::: "memory");

    // epilogue: col = n-side via rl, row = m-side via g*4+r
    const float* xaddz = xadd;
    float* outFz = outF;
    if (EPI == 3) {
        outFz += (size_t)z * batchC;
        xaddz += (size_t)z * batchC;
    }
    #pragma unroll
    for (int fm = 0; fm < 4; ++fm) {
        #pragma unroll
        for (int fn = 0; fn < 4; ++fn) {
            const int col = n0 + wc * 64 + fn * 16 + rl;
            if (EPI == 1) {
                const int row0 = m0 + wr * 64 + fm * 16 + g * 4;
                const int zz = row0 >> 11;
                const int rr = row0 & 2047;
                const float bv = bias[col];
                f16x4 o;
                #pragma unroll
                for (int r = 0; r < 4; ++r) o[r] = (f16)(acc[fm][fn][r] + bv);
                *(f16x4*)(outH + ((size_t)zz * N + col) * 2048 + rr) = o;
            } else {
                #pragma unroll
                for (int r = 0; r < 4; ++r) {
                    const int row = m0 + wr * 64 + fm * 16 + g * 4 + r;
                    const size_t idx = (size_t)row * N + col;
                    outFz[idx] = acc[fm][fn][r] + xaddz[idx];
                }
            }
        }
    }
}

// ---------------- GEMM (NT) 128^2 ring-3 (g2 only) -------------------------
template <int EPI>
__global__ __launch_bounds__(256, 3)
void gemm_nt_kernel(const f16* __restrict__ A, const f16* __restrict__ Bt,
                    f16* __restrict__ outH,
                    int M, int N, int K,
                    long long batchA, long long batchB, long long batchC) {
    __shared__ __attribute__((aligned(16))) f16 sA[3][128 * 32];
    __shared__ __attribute__((aligned(16))) f16 sB[3][128 * 32];

    const int z = blockIdx.z;
    A  += (size_t)z * batchA;
    Bt += (size_t)z * batchB;

    const int m0 = blockIdx.x * 128;
    const int n0 = blockIdx.y * 128;
    const int t = threadIdx.x;
    const int l = t & 63;
    const int wid = t >> 6;
    const int wm = (wid >> 1) * 64;
    const int wn = (wid & 1) * 64;

    f32x4 acc[4][4] = {};

    const int rl = l & 15;
    const int nk = K >> 5;

    const int row0 = t >> 2;
    const int kb = ((t & 3) ^ (row0 & 3)) * 8;
    const f16* Ag0 = A  + (size_t)(m0 + row0) * K + kb;
    const f16* Ag1 = A  + (size_t)(m0 + row0 + 64) * K + kb;
    const f16* Bg0 = Bt + (size_t)(n0 + row0) * K + kb;
    const f16* Bg1 = Bt + (size_t)(n0 + row0 + 64) * K + kb;
    const int lo0 = wid * 512;
    const int lo1 = 2048 + wid * 512;

    const int swk = (((l >> 4) ^ (rl & 3))) * 8;

    gload_lds16(Ag0,      sA[0] + lo0);
    gload_lds16(Ag1,      sA[0] + lo1);
    gload_lds16(Bg0,      sB[0] + lo0);
    gload_lds16(Bg1,      sB[0] + lo1);
    gload_lds16(Ag0 + 32, sA[1] + lo0);
    gload_lds16(Ag1 + 32, sA[1] + lo1);
    gload_lds16(Bg0 + 32, sB[1] + lo0);
    gload_lds16(Bg1 + 32, sB[1] + lo1);

    f16 *curA = sA[0], *nxtA = sA[1], *farA = sA[2];
    f16 *curB = sB[0], *nxtB = sB[1], *farB = sB[2];

    for (int kt = 0; kt < nk; ++kt) {
        asm volatile("s_waitcnt vmcnt(4)" ::: "memory");
        __builtin_amdgcn_s_barrier();

        const int ktn = (kt + 2 < nk) ? kt + 2 : nk - 1;
        const int kof = ktn * 32;
        gload_lds16(Ag0 + kof, farA + lo0);
        gload_lds16(Ag1 + kof, farA + lo1);
        gload_lds16(Bg0 + kof, farB + lo0);
        gload_lds16(Bg1 + kof, farB + lo1);

        f16x8 a[4], b[4];
        #pragma unroll
        for (int f = 0; f < 4; ++f) {
            a[f] = *(const f16x8*)&curA[(wm + f * 16 + rl) * 32 + swk];
            b[f] = *(const f16x8*)&curB[(wn + f * 16 + rl) * 32 + swk];
        }
        #pragma unroll
        for (int fm = 0; fm < 4; ++fm)
            #pragma unroll
            for (int fn = 0; fn < 4; ++fn)
                acc[fm][fn] = __builtin_amdgcn_mfma_f32_16x16x32_f16(
                    a[fm], b[fn], acc[fm][fn], 0, 0, 0);

        f16* tA = curA; curA = nxtA; nxtA = farA; farA = tA;
        f16* tB = curB; curB = nxtB; nxtB = farB; farB = tB;
    }
    asm volatile("s_waitcnt vmcnt(0)" ::: "memory");

    const int rh = l >> 4;
    f16* outHz = outH + (size_t)z * batchC;
    #pragma unroll
    for (int fm = 0; fm < 4; ++fm) {
        #pragma unroll
        for (int fn = 0; fn < 4; ++fn) {
            const int col = n0 + wn + fn * 16 + rl;
            #pragma unroll
            for (int r = 0; r < 4; ++r) {
                const int row = m0 + wm + fm * 16 + rh * 4 + r;
                outHz[(size_t)row * N + col] = (f16)acc[fm][fn][r];
            }
        }
    }
}

extern "C" void kernel_launch(void* const* d_in, const int* in_sizes, int n_in,
                              void* d_out, int out_size, void* d_ws, size_t ws_size,
                              hipStream_t stream) {
    const float* x     = (const float*)d_in[0];
    const float* gamma = (const float*)d_in[1];
    const float* beta  = (const float*)d_in[2];
    const float* w1    = (const float*)d_in[3];
    const float* b1    = (const float*)d_in[4];
    const float* w2    = (const float*)d_in[5];
    const float* b2    = (const float*)d_in[6];
    float* out = (float*)d_out;

    const int BS = 4, T = 2048, DIM = 1024, HID = 2048;
    const int M = BS * T;  // 8192
    const long long MB = 1024 * 1024;

    // workspace layout (112 MiB total)
    char* ws = (char*)d_ws;
    f16*   x_h  = (f16*)(ws + 0 * MB);    // 16 MiB [M][DIM]
    f16*   y_h  = (f16*)(ws + 16 * MB);   // 16 MiB [M][DIM]
    f16*   h    = (f16*)(ws + 32 * MB);   // 32 MiB [M][HID]
    float* pre  = (float*)h;              // alias: h dead after GEMM2
    f16*   y2t  = (f16*)(ws + 64 * MB);   // 16 MiB [BS][DIM][T]
    f16*   x_t  = (f16*)(ws + 80 * MB);   // 16 MiB [BS][DIM][T]
    f16*   G    = (f16*)(ws + 96 * MB);   // 8 MiB  [BS][DIM][DIM]
    f16*   w1t  = (f16*)(ws + 104 * MB);  // 4 MiB  [HID][DIM]
    f16*   w2t  = (f16*)(ws + 108 * MB);  // 4 MiB  [DIM][HID]

    // 1) first LN + fp16 casts
    ln_cast_kernel<<<M, 256, 0, stream>>>(x, gamma, beta, y_h, x_h);

    // 2) weight transposes to fp16 [N][K]
    transpose_cast_kernel<<<dim3(HID / 32, DIM / 32), 256, 0, stream>>>(w1, w1t, DIM, HID);
    transpose_cast_kernel<<<dim3(DIM / 32, HID / 32), 256, 0, stream>>>(w2, w2t, HID, DIM);

    // 3) h = gelu(y @ w1 + b1)   [M][HID]  -- 256^2 8-phase
    gemm256_nt_kernel<0><<<dim3(M / 256, HID / 256), 512, 0, stream>>>(
        y_h, w1t, b1, h, M, HID, DIM);

    // 4) y2t[z][f][t] = (h @ w2 + b2)[z*T+t][f]  -- 256x128 8-phase, transposed epi
    gemm256x128_nt_kernel<1><<<dim3(M / 256, DIM / 128, 1), 512, 0, stream>>>(
        h, w2t, b2, nullptr, y2t, nullptr, M, DIM, HID, 0, 0, 0);

    // 5) x_t[z][f][t] = x_h[z*T+t][f]
    transpose_f16_kernel<<<dim3(DIM / 32, T / 32, BS), 256, 0, stream>>>(x_h, x_t, T, DIM);

    // 6) G'[z][f2][f1] = sum_t y2t[z][f2][t] * x_t[z][f1][t]  -- 128^2 ring-3
    gemm_nt_kernel<2><<<dim3(DIM / 128, DIM / 128, BS), 256, 0, stream>>>(
        y2t, x_t, G, DIM, DIM, T,
        (long long)DIM * T, (long long)DIM * T, (long long)DIM * DIM);

    // 7) pre[z][t][f] = sum_k x_h[z][t][k] * G'[z][f][k] + x  -- 256x128 8-phase
    gemm256x128_nt_kernel<3><<<dim3(T / 256, DIM / 128, BS), 512, 0, stream>>>(
        x_h, G, nullptr, x, nullptr, pre, T, DIM, DIM,
        (long long)T * DIM, (long long)DIM * DIM, (long long)T * DIM);

    // 8) final LN
    ln_final_kernel<<<M, 256, 0, stream>>>(pre, gamma, beta, out);
}